// Round 1
// baseline (433.232 us; speedup 1.0000x reference)
//
#include <hip/hip_runtime.h>

// AttentionWindow (BEiT windowed attention), MI355X gfx950.
// B=64 N=197 DIM=768 H=12 hd=64. bf16 MFMA (16x16x32), fp32 softmax.
// R8: occupancy push: LDS 149KB -> exactly 80KB so 2 blocks/CU (16 waves).
//     - Q/K stride-64 XOR-swizzled (no pad), VT 64x224 group-swizzled.
//     - P-LDS (59KB) eliminated: swapped QK^T (mfma(K,Q) -> S^T, lane-local
//       q-row) => softmax reduce = 4 shfl (was 32); P redistributed to PV
//       A-frag layout in-register via ds_bpermute (8 perm + 4 sel / chunk).
//     - QKV partition (4m x 2n) -> (2m x 4n): acc 96 -> 84 regs, balance 21:18.
//     - __launch_bounds__(512,4) caps unified regs at 128 (4 waves/SIMD).
//     - s_setprio(1) around QK / PV MFMA clusters (T5).

#define B_    64
#define N_    197
#define DIM_  768
#define H_    12
#define HD_   64
#define M_TOT (B_ * N_)     // 12608

// fused LDS map (shorts): total 40960 shorts = 81920 B = exactly 80 KB
#define OFF_Q   0            // 208 rows x 64, XOR-swizzled slots
#define OFF_K   13312        // 208 rows x 64, XOR-swizzled slots
#define OFF_VT  26624        // 64 rows (d) x 224 (tok), group-swizzled slots
#define ST_A0   0            // staging overlays Q/K region (dead before epilogue)
#define ST_A1   6656
#define ST_B0   13312
#define ST_B1   19456        // end 25600
#define LDS_TOT 40960

typedef __attribute__((ext_vector_type(8))) short bf8;
typedef __attribute__((ext_vector_type(4))) float f4;

__device__ __forceinline__ unsigned short f2bf(float f) {
    unsigned u = __float_as_uint(f);
    u = (u + 0x7fffu + ((u >> 16) & 1u)) >> 16;
    return (unsigned short)u;
}

__device__ __forceinline__ void gl2lds16(const unsigned short* g, unsigned short* l) {
    __builtin_amdgcn_global_load_lds(
        (const __attribute__((address_space(1))) void*)g,
        (__attribute__((address_space(3))) void*)l, 16, 0, 0);
}

// Q/K LDS address (shorts): row-stride 64, 16B slot XOR-swizzled by row.
__device__ __forceinline__ int qkaddr(int row, int col) {
    return row * 64 + ((((col >> 3) ^ row) & 7) << 3) + (col & 7);
}
// VT LDS address (shorts): d-stride 224; 28 slots/row; XOR within slot groups
// (full 8-groups for s<24, the tail group of 4 uses a 2-bit XOR).
__device__ __forceinline__ int vtaddr(int d, int k) {
    int s = k >> 3;
    int s2 = (s < 24) ? ((s & 24) | ((s ^ d) & 7)) : (24 + ((s ^ d) & 3));
    return d * 224 + (s2 << 3) + (k & 7);
}

// ---------------- prep: fp32->bf16 converts, bias gather ----------------
__global__ void k_prep(const float* __restrict__ x, const float* __restrict__ qkvw,
                       const float* __restrict__ projw, const float* __restrict__ rpb,
                       const int* __restrict__ relidx,
                       unsigned short* __restrict__ x_bf, unsigned short* __restrict__ qkvw_bf,
                       unsigned short* __restrict__ projw_bf, float* __restrict__ bias_hqk) {
    const int T = gridDim.x * blockDim.x;
    const int tid = blockIdx.x * blockDim.x + threadIdx.x;
    for (int i = tid; i < M_TOT * DIM_; i += T) x_bf[i] = f2bf(x[i]);
    for (int i = tid; i < 3 * DIM_ * DIM_; i += T) qkvw_bf[i] = f2bf(qkvw[i]);
    for (int i = tid; i < DIM_ * DIM_; i += T) projw_bf[i] = f2bf(projw[i]);
    for (int i = tid; i < H_ * N_ * N_; i += T) {
        int h = i / (N_ * N_), qk = i - h * (N_ * N_);
        bias_hqk[i] = rpb[relidx[qk] * H_ + h];
    }
}

// ---------------- fused QKV + attention, one block (512 thr) per (b,h) ----------------
__global__ __launch_bounds__(512, 4) void k_fused(const unsigned short* __restrict__ X,
                                                  const unsigned short* __restrict__ Wqkv,
                                                  const float* __restrict__ qb,
                                                  const float* __restrict__ vbias,
                                                  const float* __restrict__ bias_hqk,
                                                  unsigned short* __restrict__ att_ws) {
    __shared__ unsigned short lds[LDS_TOT];

    const int t = threadIdx.x;                 // 0..511
    const int w = t >> 6, lane = t & 63, ln = lane & 15, quad = lane >> 4;
    const int wm2 = w & 1, wn2 = w >> 1;       // (2 m-groups) x (4 n-groups)
    const int srl = lane >> 3;                 // local superrow 0..7
    const int src8 = (lane & 7) ^ srl;         // stored-slot -> fetched-chunk XOR swizzle

    // XCD swizzle: gid%8 -> XCD; contiguous 8-b group per XCD keeps x in its L2
    const int gid = blockIdx.x;                // 0..767
    const int local = gid >> 3;                // 0..95
    const int b = (gid & 7) * 8 + (local & 7);
    const int h = local >> 3;                  // 0..11

    const unsigned short* xb = X + (size_t)b * 197 * 768;

    // ---- staging: 25 DMA instrs/phase (13 A-superrow-groups + 12 B), split over 8 waves
    auto stage = [&](int kt, int aOfs, int bOfs) {
#pragma unroll
        for (int i = 0; i < 4; ++i) {
            int idx = w + 8 * i;
            if (idx >= 25) break;              // wave-uniform
            if (idx < 13) {                    // A: superrows idx*8..+7 (tokens 2sr,2sr+1)
                int tok = 2 * (idx * 8 + srl) + (src8 >> 2);
                if (tok > 196) tok = 196;      // clamp; pad rows discarded later
                gl2lds16(xb + (size_t)tok * 768 + kt * 32 + (src8 & 3) * 8,
                         &lds[aOfs + idx * 512]);
            } else {                           // B: weight rows (3 passes x 64)
                int bb = idx - 13;
                int rr = 2 * (bb * 8 + srl) + (src8 >> 2);   // 0..191
                gl2lds16(Wqkv + (size_t)((rr >> 6) * 768 + h * 64 + (rr & 63)) * 768
                              + kt * 32 + (src8 & 3) * 8,
                         &lds[bOfs + bb * 512]);
            }
        }
    };

    f4 acc[7][3] = {};                         // [mi][tn_local]: wave tile = (2m x 4n)

    auto compute = [&](int aOfs, int bOfs) {
        bf8 bfr[3];
#pragma unroll
        for (int tl = 0; tl < 3; ++tl) {
            int rr = (wn2 * 3 + tl) * 16 + ln;
            int sr = rr >> 1;
            int slot = (((rr & 1) << 2) | quad) ^ (sr & 7);
            bfr[tl] = *(const bf8*)&lds[bOfs + sr * 64 + slot * 8];
        }
#pragma unroll
        for (int mi = 0; mi < 7; ++mi) {
            int mt = wm2 + 2 * mi;
            if (mt >= 13) continue;            // wave-uniform (only wm2=1, mi=6)
            int row = mt * 16 + ln;
            int sr = row >> 1;
            int slot = (((row & 1) << 2) | quad) ^ (sr & 7);
            bf8 af = *(const bf8*)&lds[aOfs + sr * 64 + slot * 8];
#pragma unroll
            for (int tl = 0; tl < 3; ++tl)
                acc[mi][tl] = __builtin_amdgcn_mfma_f32_16x16x32_bf16(
                    af, bfr[tl], acc[mi][tl], 0, 0, 0);
        }
    };

    stage(0, ST_A0, ST_B0);
    for (int kt2 = 0; kt2 < 24; kt2 += 2) {
        __syncthreads();                       // drains buf0 DMA
        if (kt2 + 1 < 24) stage(kt2 + 1, ST_A1, ST_B1);
        compute(ST_A0, ST_B0);
        __syncthreads();                       // drains buf1 DMA
        if (kt2 + 2 < 24) stage(kt2 + 2, ST_A0, ST_B0);
        if (kt2 + 1 < 24) compute(ST_A1, ST_B1);
    }
    __syncthreads();                           // staging dead: epilogue overlays it

    // ---- epilogue: C/D layout row=quad*4+r, col=ln (m89-verified) -> LDS Q/K/VT
#pragma unroll
    for (int tl = 0; tl < 3; ++tl) {
        int tn = wn2 * 3 + tl;
        int p = tn >> 2;                       // 0=Q 1=K 2=V
        int col = (tn & 3) * 16 + ln;          // 0..63 within the pass
        int d = h * 64 + col;
        float bj = (p == 0) ? qb[d] : (p == 2) ? vbias[d] : 0.0f;
#pragma unroll
        for (int mi = 0; mi < 7; ++mi) {
            int mt = wm2 + 2 * mi;
            if (mt >= 13) continue;
#pragma unroll
            for (int r = 0; r < 4; ++r) {
                int row = mt * 16 + quad * 4 + r;  // 0..207 (pad rows masked later)
                float v = acc[mi][tl][r];
                if (p == 0)      lds[OFF_Q + qkaddr(row, col)] = f2bf((v + bj) * 0.125f);
                else if (p == 1) lds[OFF_K + qkaddr(row, col)] = f2bf(v);
                else             lds[OFF_VT + vtaddr(col, row)] = f2bf(v + bj);
            }
        }
    }
    // zero VT K-pad cols 208..223 (cols 197..207 hold finite clamped data)
    for (int idx = t; idx < 64 * 16; idx += 512) {
        int d = idx >> 4, k = 208 + (idx & 15);
        lds[OFF_VT + vtaddr(d, k)] = 0;
    }
    __syncthreads();

    // ---- attention (Q/K/VT in LDS, P fully in-register), 8 waves over 13 m-tiles ----
    const float* bp = bias_hqk + (size_t)h * 197 * 197;

    for (int mt = w; mt < 13; mt += 8) {
        // Q as B-operand (hoisted): lane ln supplies q-row mt*16+ln
        bf8 qa[2];
#pragma unroll
        for (int ks = 0; ks < 2; ++ks)
            qa[ks] = *(const bf8*)&lds[OFF_Q + qkaddr(mt * 16 + ln, ks * 32 + quad * 8)];

        // swapped QK: S^T[k][q];  lane(ln,quad) reg r holds S[q=mt*16+ln][k=nt*16+quad*4+r]
        f4 sacc[13];
#pragma unroll
        for (int nt = 0; nt < 13; ++nt) sacc[nt] = (f4){0.f, 0.f, 0.f, 0.f};
        __builtin_amdgcn_s_setprio(1);
#pragma unroll
        for (int nt = 0; nt < 13; ++nt) {
#pragma unroll
            for (int ks = 0; ks < 2; ++ks) {
                bf8 ka = *(const bf8*)&lds[OFF_K + qkaddr(nt * 16 + ln, ks * 32 + quad * 8)];
                sacc[nt] = __builtin_amdgcn_mfma_f32_16x16x32_bf16(ka, qa[ks], sacc[nt], 0, 0, 0);
            }
        }
        __builtin_amdgcn_s_setprio(0);

        // softmax: row is lane-local across (nt,r); cross-lane only over quad (2 shfl)
        int qg = mt * 16 + ln;
        const float* brow = bp + (size_t)(qg < 197 ? qg : 196) * 197;
        float mx = -3.0e38f;
#pragma unroll
        for (int nt = 0; nt < 13; ++nt)
#pragma unroll
            for (int r = 0; r < 4; ++r) {
                int kg = nt * 16 + quad * 4 + r;
                float s = (kg < 197) ? (sacc[nt][r] + brow[kg]) : -3.0e38f;
                sacc[nt][r] = s;
                mx = fmaxf(mx, s);
            }
        mx = fmaxf(mx, __shfl_xor(mx, 16, 64));
        mx = fmaxf(mx, __shfl_xor(mx, 32, 64));
        float sum = 0.f;
#pragma unroll
        for (int nt = 0; nt < 13; ++nt)
#pragma unroll
            for (int r = 0; r < 4; ++r) {
                float pv = __expf(sacc[nt][r] - mx);
                sacc[nt][r] = pv;
                sum += pv;
            }
        sum += __shfl_xor(sum, 16, 64);
        sum += __shfl_xor(sum, 32, 64);
        float inv = 1.0f / sum;

        // pack normalized P to bf16 pairs: pk[nt][0]=(r0,r1), pk[nt][1]=(r2,r3)
        unsigned pk[14][2];
#pragma unroll
        for (int nt = 0; nt < 13; ++nt) {
            pk[nt][0] = (unsigned)f2bf(sacc[nt][0] * inv) |
                        ((unsigned)f2bf(sacc[nt][1] * inv) << 16);
            pk[nt][1] = (unsigned)f2bf(sacc[nt][2] * inv) |
                        ((unsigned)f2bf(sacc[nt][3] * inv) << 16);
        }
        pk[13][0] = 0; pk[13][1] = 0;          // K-pad 208..223 -> P = 0

        // PV: A-frag (lane ln = q-row ln, k-chunk = quad*8) built by ds_bpermute:
        // target quad q_t takes k=32ks+8q_t+[0..7] from source lanes
        // (ln + 32*(q_t&1)) and (+16), register set nt = 2ks + (q_t>>1).
        const int sA = (((lane & 15) | ((lane & 16) << 1)) << 2);
        const int sB = sA + 64;
        const bool hi = (lane & 32) != 0;
        f4 o[4];
#pragma unroll
        for (int j = 0; j < 4; ++j) o[j] = (f4){0.f, 0.f, 0.f, 0.f};
#pragma unroll
        for (int ks = 0; ks < 7; ++ks) {
            int b0 = __builtin_amdgcn_ds_bpermute(sA, (int)pk[2 * ks][0]);
            int b1 = __builtin_amdgcn_ds_bpermute(sA, (int)pk[2 * ks][1]);
            int b2 = __builtin_amdgcn_ds_bpermute(sB, (int)pk[2 * ks][0]);
            int b3 = __builtin_amdgcn_ds_bpermute(sB, (int)pk[2 * ks][1]);
            int c0 = __builtin_amdgcn_ds_bpermute(sA, (int)pk[2 * ks + 1][0]);
            int c1 = __builtin_amdgcn_ds_bpermute(sA, (int)pk[2 * ks + 1][1]);
            int c2 = __builtin_amdgcn_ds_bpermute(sB, (int)pk[2 * ks + 1][0]);
            int c3 = __builtin_amdgcn_ds_bpermute(sB, (int)pk[2 * ks + 1][1]);
            union { int u[4]; bf8 v; } uu;
            uu.u[0] = hi ? c0 : b0;
            uu.u[1] = hi ? c1 : b1;
            uu.u[2] = hi ? c2 : b2;
            uu.u[3] = hi ? c3 : b3;
            __builtin_amdgcn_s_setprio(1);
#pragma unroll
            for (int j = 0; j < 4; ++j) {
                bf8 vf = *(const bf8*)&lds[OFF_VT + vtaddr(j * 16 + ln, ks * 32 + quad * 8)];
                o[j] = __builtin_amdgcn_mfma_f32_16x16x32_bf16(uu.v, vf, o[j], 0, 0, 0);
            }
            __builtin_amdgcn_s_setprio(0);
        }
#pragma unroll
        for (int j = 0; j < 4; ++j)
#pragma unroll
            for (int r = 0; r < 4; ++r) {
                int tok = mt * 16 + quad * 4 + r;
                if (tok < 197)
                    att_ws[((size_t)b * 197 + tok) * 768 + h * 64 + j * 16 + ln] = f2bf(o[j][r]);
            }
    }
}

// ---------------- proj GEMM: (12608x768) @ (768x768)^T + bias -> fp32 out ----------------
__device__ __forceinline__ void pj_stage(const unsigned short* __restrict__ A,
                                         const unsigned short* __restrict__ Bm,
                                         int bm, int bn, int kt, int w, int rsub, int src8,
                                         unsigned short* a_l, unsigned short* b_l) {
#pragma unroll
    for (int c = 0; c < 4; ++c) {
        int rb = w * 32 + c * 8;
        int gr = bm * 128 + rb + rsub;
        if (gr > M_TOT - 1) gr = M_TOT - 1;
        gl2lds16(A + (size_t)gr * 768 + kt * 64 + (src8 << 3), &a_l[rb * 64]);
        int gc = bn * 128 + rb + rsub;      // < 768
        gl2lds16(Bm + (size_t)gc * 768 + kt * 64 + (src8 << 3), &b_l[rb * 64]);
    }
}

__device__ __forceinline__ void pj_compute(const unsigned short* a_l, const unsigned short* b_l,
                                           int wm, int wn, int ln, int quad, f4 (*acc)[4]) {
#pragma unroll
    for (int ks = 0; ks < 2; ++ks) {
        bf8 af[4], bfr[4];
#pragma unroll
        for (int i = 0; i < 4; ++i)
            af[i] = *(const bf8*)&a_l[((wm * 64 + i * 16 + ln) << 6) +
                                      ((((ks << 2) + quad) ^ (ln & 7)) << 3)];
#pragma unroll
        for (int j = 0; j < 4; ++j)
            bfr[j] = *(const bf8*)&b_l[((wn * 64 + j * 16 + ln) << 6) +
                                       ((((ks << 2) + quad) ^ (ln & 7)) << 3)];
#pragma unroll
        for (int i = 0; i < 4; ++i)
#pragma unroll
            for (int j = 0; j < 4; ++j)
                acc[i][j] = __builtin_amdgcn_mfma_f32_16x16x32_bf16(af[i], bfr[j], acc[i][j], 0, 0, 0);
    }
}

__global__ __launch_bounds__(256) void k_proj(const unsigned short* __restrict__ A,
                                              const unsigned short* __restrict__ Bm,
                                              const float* __restrict__ pb,
                                              float* __restrict__ out) {
    __shared__ unsigned short a0[128 * 64], a1[128 * 64];
    __shared__ unsigned short b0[128 * 64], b1[128 * 64];
    const int t = threadIdx.x;
    const int w = t >> 6, lane = t & 63, ln = lane & 15, quad = lane >> 4;
    const int wm = w & 1, wn = w >> 1;

    const int gid = blockIdx.x;                 // panels: 8 bm x 6 bn = 48
    const int panel = gid / 48, rem = gid - panel * 48;
    const int pm0 = panel * 8;
    const int psz = (99 - pm0 < 8) ? (99 - pm0) : 8;
    const int bm = pm0 + rem % psz;
    const int bn = rem / psz;

    const int rsub = lane >> 3;
    const int src8 = (lane & 7) ^ rsub;

    f4 acc[4][4] = {};

    pj_stage(A, Bm, bm, bn, 0, w, rsub, src8, a0, b0);
#pragma unroll
    for (int kt2 = 0; kt2 < 12; kt2 += 2) {
        __syncthreads();
        if (kt2 + 1 < 12) pj_stage(A, Bm, bm, bn, kt2 + 1, w, rsub, src8, a1, b1);
        pj_compute(a0, b0, wm, wn, ln, quad, acc);
        __syncthreads();
        if (kt2 + 2 < 12) pj_stage(A, Bm, bm, bn, kt2 + 2, w, rsub, src8, a0, b0);
        if (kt2 + 1 < 12) pj_compute(a1, b1, wm, wn, ln, quad, acc);
    }

#pragma unroll
    for (int i = 0; i < 4; ++i) {
#pragma unroll
        for (int r = 0; r < 4; ++r) {
            int row_g = bm * 128 + wm * 64 + i * 16 + quad * 4 + r;
            if (row_g >= M_TOT) continue;
#pragma unroll
            for (int j = 0; j < 4; ++j) {
                int col_g = bn * 128 + wn * 64 + j * 16 + ln;
                out[(size_t)row_g * 768 + col_g] = acc[i][j][r] + pb[col_g];
            }
        }
    }
}

extern "C" void kernel_launch(void* const* d_in, const int* in_sizes, int n_in,
                              void* d_out, int out_size, void* d_ws, size_t ws_size,
                              hipStream_t stream) {
    const float* x     = (const float*)d_in[0];
    const float* qkvw  = (const float*)d_in[1];
    const float* qb    = (const float*)d_in[2];
    const float* vb    = (const float*)d_in[3];
    const float* rpb   = (const float*)d_in[4];
    const float* projw = (const float*)d_in[5];
    const float* pb    = (const float*)d_in[6];
    const int*   ridx  = (const int*)d_in[7];
    float* out = (float*)d_out;

    char* ws = (char*)d_ws;
    size_t off = 0;
    auto alloc = [&](size_t bytes) -> void* {
        void* p = ws + off;
        off = (off + bytes + 255) & ~(size_t)255;
        return p;
    };
    unsigned short* x_bf     = (unsigned short*)alloc((size_t)M_TOT * DIM_ * 2);
    unsigned short* qkvw_bf  = (unsigned short*)alloc((size_t)3 * DIM_ * DIM_ * 2);
    unsigned short* projw_bf = (unsigned short*)alloc((size_t)DIM_ * DIM_ * 2);
    float*          bias_h   = (float*)alloc((size_t)H_ * N_ * N_ * 4);
    unsigned short* att_ws   = (unsigned short*)alloc((size_t)(M_TOT + 64) * DIM_ * 2);
    (void)ws_size; (void)in_sizes; (void)n_in; (void)out_size;

    k_prep<<<1200, 256, 0, stream>>>(x, qkvw, projw, rpb, ridx,
                                     x_bf, qkvw_bf, projw_bf, bias_h);
    k_fused<<<768, 512, 0, stream>>>(x_bf, qkvw_bf, qb, vb, bias_h, att_ws);
    k_proj<<<594, 256, 0, stream>>>(att_ws, projw_bf, pb, out);
}

// Round 2
// 222.289 us; speedup vs baseline: 1.9490x; 1.9490x over previous
//
#include <hip/hip_runtime.h>

// AttentionWindow (BEiT windowed attention), MI355X gfx950.
// B=64 N=197 DIM=768 H=12 hd=64. bf16 MFMA (16x16x32), fp32 softmax.
// R9: 1024-thread blocks (16 waves = 4 waves/SIMD from ONE block) so the
//     occupancy doubles without a 128-reg wall: QKV acc = 12 tiles = 48 regs
//     per thread (was 84 at 512 thr). BK=64 staging (12 K-steps, barriers
//     halved); staging (102 KB) overlays Q/K/VT (82 KB) -> LDS 102.4 KB.
//     Attention phase is R8's *verified* swapped-QK + in-register softmax/P
//     + ds_bpermute PV (absmax-identical pass), now 13 m-tiles in one round.

#define B_    64
#define N_    197
#define DIM_  768
#define H_    12
#define HD_   64
#define M_TOT (B_ * N_)     // 12608

// fused LDS map (shorts): staging 51200 shorts = 102400 B; Q/K/VT overlays it
#define ST_A0   0            // 208 x 64
#define ST_A1   13312
#define ST_B0   26624        // 192 x 64 (Q|K|V weight rows)
#define ST_B1   38912        // end 51200
#define OFF_Q   0            // 208 rows x 64, XOR-swizzled slots (overlay ST_A0)
#define OFF_K   13312        // 208 rows x 64 (overlay ST_A1)
#define OFF_VT  26624        // 64 rows (d) x 224 (tok), group-swizzled (overlay ST_B0)
#define LDS_TOT 51200

typedef __attribute__((ext_vector_type(8))) short bf8;
typedef __attribute__((ext_vector_type(4))) float f4;

__device__ __forceinline__ unsigned short f2bf(float f) {
    unsigned u = __float_as_uint(f);
    u = (u + 0x7fffu + ((u >> 16) & 1u)) >> 16;
    return (unsigned short)u;
}

__device__ __forceinline__ void gl2lds16(const unsigned short* g, unsigned short* l) {
    __builtin_amdgcn_global_load_lds(
        (const __attribute__((address_space(1))) void*)g,
        (__attribute__((address_space(3))) void*)l, 16, 0, 0);
}

// Q/K LDS address (shorts): row-stride 64, 16B slot XOR-swizzled by row.
__device__ __forceinline__ int qkaddr(int row, int col) {
    return row * 64 + ((((col >> 3) ^ row) & 7) << 3) + (col & 7);
}
// VT LDS address (shorts): d-stride 224; 28 slots/row; XOR within slot groups
// (full 8-groups for s<24, the tail group of 4 uses a 2-bit XOR).
__device__ __forceinline__ int vtaddr(int d, int k) {
    int s = k >> 3;
    int s2 = (s < 24) ? ((s & 24) | ((s ^ d) & 7)) : (24 + ((s ^ d) & 3));
    return d * 224 + (s2 << 3) + (k & 7);
}

// ---------------- prep: fp32->bf16 converts, bias gather ----------------
__global__ void k_prep(const float* __restrict__ x, const float* __restrict__ qkvw,
                       const float* __restrict__ projw, const float* __restrict__ rpb,
                       const int* __restrict__ relidx,
                       unsigned short* __restrict__ x_bf, unsigned short* __restrict__ qkvw_bf,
                       unsigned short* __restrict__ projw_bf, float* __restrict__ bias_hqk) {
    const int T = gridDim.x * blockDim.x;
    const int tid = blockIdx.x * blockDim.x + threadIdx.x;
    for (int i = tid; i < M_TOT * DIM_; i += T) x_bf[i] = f2bf(x[i]);
    for (int i = tid; i < 3 * DIM_ * DIM_; i += T) qkvw_bf[i] = f2bf(qkvw[i]);
    for (int i = tid; i < DIM_ * DIM_; i += T) projw_bf[i] = f2bf(projw[i]);
    for (int i = tid; i < H_ * N_ * N_; i += T) {
        int h = i / (N_ * N_), qk = i - h * (N_ * N_);
        bias_hqk[i] = rpb[relidx[qk] * H_ + h];
    }
}

// ---------------- fused QKV + attention, one block (1024 thr) per (b,h) ----------------
__global__ __launch_bounds__(1024) void k_fused(const unsigned short* __restrict__ X,
                                                const unsigned short* __restrict__ Wqkv,
                                                const float* __restrict__ qb,
                                                const float* __restrict__ vbias,
                                                const float* __restrict__ bias_hqk,
                                                unsigned short* __restrict__ att_ws) {
    __shared__ unsigned short lds[LDS_TOT];

    const int t = threadIdx.x;                 // 0..1023
    const int w = t >> 6, lane = t & 63, ln = lane & 15, quad = lane >> 4;
    const int wm = w & 3, wn = w >> 2;         // (4 m-groups) x (4 n-groups)
    const int srl = lane >> 3;                 // local row 0..7 within 8-row group
    const int src8 = (lane & 7) ^ srl;         // stored-slot -> fetched-chunk XOR swizzle

    // XCD swizzle: gid%8 -> XCD; contiguous 8-b group per XCD keeps x in its L2
    const int gid = blockIdx.x;                // 0..767
    const int local = gid >> 3;                // 0..95
    const int b = (gid & 7) * 8 + (local & 7);
    const int h = local >> 3;                  // 0..11

    const unsigned short* xb = X + (size_t)b * 197 * 768;

    // ---- staging (BK=64): 50 DMA instrs/phase (26 A row-groups + 24 B), 16 waves
    auto stage = [&](int kt, int aOfs, int bOfs) {
#pragma unroll
        for (int i = 0; i < 4; ++i) {
            int idx = w + 16 * i;
            if (idx >= 50) break;              // wave-uniform
            if (idx < 26) {                    // A: token rows idx*8..+7
                int tok = 8 * idx + srl;
                if (tok > 196) tok = 196;      // clamp; pad rows discarded later
                gl2lds16(xb + (size_t)tok * 768 + kt * 64 + src8 * 8,
                         &lds[aOfs + idx * 512]);
            } else {                           // B: weight rows (3 passes x 64)
                int bb = idx - 26;
                int rr = 8 * bb + srl;         // 0..191
                gl2lds16(Wqkv + (size_t)((rr >> 6) * 768 + h * 64 + (rr & 63)) * 768
                              + kt * 64 + src8 * 8,
                         &lds[bOfs + bb * 512]);
            }
        }
    };

    f4 acc[4][3] = {};                         // [mi][tl]: wave tile = (4m x 4n), 12 tiles

    auto compute = [&](int aOfs, int bOfs) {
#pragma unroll
        for (int ks = 0; ks < 2; ++ks) {
            bf8 bfr[3];
#pragma unroll
            for (int tl = 0; tl < 3; ++tl) {
                int rr = (wn * 3 + tl) * 16 + ln;
                int slot = (ks * 4 + quad) ^ (rr & 7);
                bfr[tl] = *(const bf8*)&lds[bOfs + rr * 64 + slot * 8];
            }
#pragma unroll
            for (int mi = 0; mi < 4; ++mi) {
                int mt = wm + 4 * mi;
                if (mt >= 13) continue;        // wave-uniform (only wm>0, mi=3)
                int row = mt * 16 + ln;
                int slot = (ks * 4 + quad) ^ (row & 7);
                bf8 af = *(const bf8*)&lds[aOfs + row * 64 + slot * 8];
#pragma unroll
                for (int tl = 0; tl < 3; ++tl)
                    acc[mi][tl] = __builtin_amdgcn_mfma_f32_16x16x32_bf16(
                        af, bfr[tl], acc[mi][tl], 0, 0, 0);
            }
        }
    };

    stage(0, ST_A0, ST_B0);
    for (int kt2 = 0; kt2 < 12; kt2 += 2) {
        __syncthreads();                       // drains buf0 DMA
        if (kt2 + 1 < 12) stage(kt2 + 1, ST_A1, ST_B1);
        compute(ST_A0, ST_B0);
        __syncthreads();                       // drains buf1 DMA
        if (kt2 + 2 < 12) stage(kt2 + 2, ST_A0, ST_B0);
        if (kt2 + 1 < 12) compute(ST_A1, ST_B1);
    }
    __syncthreads();                           // staging dead: epilogue overlays it

    // ---- epilogue: C/D layout row=quad*4+r, col=ln (m89-verified) -> LDS Q/K/VT
#pragma unroll
    for (int tl = 0; tl < 3; ++tl) {
        int tn = wn * 3 + tl;
        int p = tn >> 2;                       // 0=Q 1=K 2=V
        int col = (tn & 3) * 16 + ln;          // 0..63 within the pass
        int d = h * 64 + col;
        float bj = (p == 0) ? qb[d] : (p == 2) ? vbias[d] : 0.0f;
#pragma unroll
        for (int mi = 0; mi < 4; ++mi) {
            int mt = wm + 4 * mi;
            if (mt >= 13) continue;
#pragma unroll
            for (int r = 0; r < 4; ++r) {
                int row = mt * 16 + quad * 4 + r;  // 0..207 (pad rows masked later)
                float v = acc[mi][tl][r];
                if (p == 0)      lds[OFF_Q + qkaddr(row, col)] = f2bf((v + bj) * 0.125f);
                else if (p == 1) lds[OFF_K + qkaddr(row, col)] = f2bf(v);
                else             lds[OFF_VT + vtaddr(col, row)] = f2bf(v + bj);
            }
        }
    }
    // zero VT K-pad cols 208..223 (cols 197..207 hold finite clamped data)
    for (int idx = t; idx < 64 * 16; idx += 1024) {
        int d = idx >> 4, k = 208 + (idx & 15);
        lds[OFF_VT + vtaddr(d, k)] = 0;
    }
    __syncthreads();

    // ---- attention (Q/K/VT in LDS, P fully in-register), 16 waves, 13 m-tiles ----
    const float* bp = bias_hqk + (size_t)h * 197 * 197;

    for (int mt = w; mt < 13; mt += 16) {
        // Q as B-operand (hoisted): lane ln supplies q-row mt*16+ln
        bf8 qa[2];
#pragma unroll
        for (int ks = 0; ks < 2; ++ks)
            qa[ks] = *(const bf8*)&lds[OFF_Q + qkaddr(mt * 16 + ln, ks * 32 + quad * 8)];

        // swapped QK: S^T[k][q];  lane(ln,quad) reg r holds S[q=mt*16+ln][k=nt*16+quad*4+r]
        f4 sacc[13];
#pragma unroll
        for (int nt = 0; nt < 13; ++nt) sacc[nt] = (f4){0.f, 0.f, 0.f, 0.f};
        __builtin_amdgcn_s_setprio(1);
#pragma unroll
        for (int nt = 0; nt < 13; ++nt) {
#pragma unroll
            for (int ks = 0; ks < 2; ++ks) {
                bf8 ka = *(const bf8*)&lds[OFF_K + qkaddr(nt * 16 + ln, ks * 32 + quad * 8)];
                sacc[nt] = __builtin_amdgcn_mfma_f32_16x16x32_bf16(ka, qa[ks], sacc[nt], 0, 0, 0);
            }
        }
        __builtin_amdgcn_s_setprio(0);

        // softmax: row is lane-local across (nt,r); cross-lane only over quad (2 shfl)
        int qg = mt * 16 + ln;
        const float* brow = bp + (size_t)(qg < 197 ? qg : 196) * 197;
        float mx = -3.0e38f;
#pragma unroll
        for (int nt = 0; nt < 13; ++nt)
#pragma unroll
            for (int r = 0; r < 4; ++r) {
                int kg = nt * 16 + quad * 4 + r;
                float s = (kg < 197) ? (sacc[nt][r] + brow[kg]) : -3.0e38f;
                sacc[nt][r] = s;
                mx = fmaxf(mx, s);
            }
        mx = fmaxf(mx, __shfl_xor(mx, 16, 64));
        mx = fmaxf(mx, __shfl_xor(mx, 32, 64));
        float sum = 0.f;
#pragma unroll
        for (int nt = 0; nt < 13; ++nt)
#pragma unroll
            for (int r = 0; r < 4; ++r) {
                float pv = __expf(sacc[nt][r] - mx);
                sacc[nt][r] = pv;
                sum += pv;
            }
        sum += __shfl_xor(sum, 16, 64);
        sum += __shfl_xor(sum, 32, 64);
        float inv = 1.0f / sum;

        // pack normalized P to bf16 pairs: pk[nt][0]=(r0,r1), pk[nt][1]=(r2,r3)
        unsigned pk[14][2];
#pragma unroll
        for (int nt = 0; nt < 13; ++nt) {
            pk[nt][0] = (unsigned)f2bf(sacc[nt][0] * inv) |
                        ((unsigned)f2bf(sacc[nt][1] * inv) << 16);
            pk[nt][1] = (unsigned)f2bf(sacc[nt][2] * inv) |
                        ((unsigned)f2bf(sacc[nt][3] * inv) << 16);
        }
        pk[13][0] = 0; pk[13][1] = 0;          // K-pad 208..223 -> P = 0

        // PV: A-frag (lane ln = q-row ln, k-chunk = quad*8) built by ds_bpermute:
        // target quad q_t takes k=32ks+8q_t+[0..7] from source lanes
        // (ln + 32*(q_t&1)) and (+16), register set nt = 2ks + (q_t>>1).
        const int sA = (((lane & 15) | ((lane & 16) << 1)) << 2);
        const int sB = sA + 64;
        const bool hi = (lane & 32) != 0;
        f4 o[4];
#pragma unroll
        for (int j = 0; j < 4; ++j) o[j] = (f4){0.f, 0.f, 0.f, 0.f};
#pragma unroll
        for (int ks = 0; ks < 7; ++ks) {
            int b0 = __builtin_amdgcn_ds_bpermute(sA, (int)pk[2 * ks][0]);
            int b1 = __builtin_amdgcn_ds_bpermute(sA, (int)pk[2 * ks][1]);
            int b2 = __builtin_amdgcn_ds_bpermute(sB, (int)pk[2 * ks][0]);
            int b3 = __builtin_amdgcn_ds_bpermute(sB, (int)pk[2 * ks][1]);
            int c0 = __builtin_amdgcn_ds_bpermute(sA, (int)pk[2 * ks + 1][0]);
            int c1 = __builtin_amdgcn_ds_bpermute(sA, (int)pk[2 * ks + 1][1]);
            int c2 = __builtin_amdgcn_ds_bpermute(sB, (int)pk[2 * ks + 1][0]);
            int c3 = __builtin_amdgcn_ds_bpermute(sB, (int)pk[2 * ks + 1][1]);
            union { int u[4]; bf8 v; } uu;
            uu.u[0] = hi ? c0 : b0;
            uu.u[1] = hi ? c1 : b1;
            uu.u[2] = hi ? c2 : b2;
            uu.u[3] = hi ? c3 : b3;
            __builtin_amdgcn_s_setprio(1);
#pragma unroll
            for (int j = 0; j < 4; ++j) {
                bf8 vf = *(const bf8*)&lds[OFF_VT + vtaddr(j * 16 + ln, ks * 32 + quad * 8)];
                o[j] = __builtin_amdgcn_mfma_f32_16x16x32_bf16(uu.v, vf, o[j], 0, 0, 0);
            }
            __builtin_amdgcn_s_setprio(0);
        }
#pragma unroll
        for (int j = 0; j < 4; ++j)
#pragma unroll
            for (int r = 0; r < 4; ++r) {
                int tok = mt * 16 + quad * 4 + r;
                if (tok < 197)
                    att_ws[((size_t)b * 197 + tok) * 768 + h * 64 + j * 16 + ln] = f2bf(o[j][r]);
            }
    }
}

// ---------------- proj GEMM: (12608x768) @ (768x768)^T + bias -> fp32 out ----------------
__device__ __forceinline__ void pj_stage(const unsigned short* __restrict__ A,
                                         const unsigned short* __restrict__ Bm,
                                         int bm, int bn, int kt, int w, int rsub, int src8,
                                         unsigned short* a_l, unsigned short* b_l) {
#pragma unroll
    for (int c = 0; c < 4; ++c) {
        int rb = w * 32 + c * 8;
        int gr = bm * 128 + rb + rsub;
        if (gr > M_TOT - 1) gr = M_TOT - 1;
        gl2lds16(A + (size_t)gr * 768 + kt * 64 + (src8 << 3), &a_l[rb * 64]);
        int gc = bn * 128 + rb + rsub;      // < 768
        gl2lds16(Bm + (size_t)gc * 768 + kt * 64 + (src8 << 3), &b_l[rb * 64]);
    }
}

__device__ __forceinline__ void pj_compute(const unsigned short* a_l, const unsigned short* b_l,
                                           int wm, int wn, int ln, int quad, f4 (*acc)[4]) {
#pragma unroll
    for (int ks = 0; ks < 2; ++ks) {
        bf8 af[4], bfr[4];
#pragma unroll
        for (int i = 0; i < 4; ++i)
            af[i] = *(const bf8*)&a_l[((wm * 64 + i * 16 + ln) << 6) +
                                      ((((ks << 2) + quad) ^ (ln & 7)) << 3)];
#pragma unroll
        for (int j = 0; j < 4; ++j)
            bfr[j] = *(const bf8*)&b_l[((wn * 64 + j * 16 + ln) << 6) +
                                       ((((ks << 2) + quad) ^ (ln & 7)) << 3)];
#pragma unroll
        for (int i = 0; i < 4; ++i)
#pragma unroll
            for (int j = 0; j < 4; ++j)
                acc[i][j] = __builtin_amdgcn_mfma_f32_16x16x32_bf16(af[i], bfr[j], acc[i][j], 0, 0, 0);
    }
}

__global__ __launch_bounds__(256) void k_proj(const unsigned short* __restrict__ A,
                                              const unsigned short* __restrict__ Bm,
                                              const float* __restrict__ pb,
                                              float* __restrict__ out) {
    __shared__ unsigned short a0[128 * 64], a1[128 * 64];
    __shared__ unsigned short b0[128 * 64], b1[128 * 64];
    const int t = threadIdx.x;
    const int w = t >> 6, lane = t & 63, ln = lane & 15, quad = lane >> 4;
    const int wm = w & 1, wn = w >> 1;

    const int gid = blockIdx.x;                 // panels: 8 bm x 6 bn = 48
    const int panel = gid / 48, rem = gid - panel * 48;
    const int pm0 = panel * 8;
    const int psz = (99 - pm0 < 8) ? (99 - pm0) : 8;
    const int bm = pm0 + rem % psz;
    const int bn = rem / psz;

    const int rsub = lane >> 3;
    const int src8 = (lane & 7) ^ rsub;

    f4 acc[4][4] = {};

    pj_stage(A, Bm, bm, bn, 0, w, rsub, src8, a0, b0);
#pragma unroll
    for (int kt2 = 0; kt2 < 12; kt2 += 2) {
        __syncthreads();
        if (kt2 + 1 < 12) pj_stage(A, Bm, bm, bn, kt2 + 1, w, rsub, src8, a1, b1);
        pj_compute(a0, b0, wm, wn, ln, quad, acc);
        __syncthreads();
        if (kt2 + 2 < 12) pj_stage(A, Bm, bm, bn, kt2 + 2, w, rsub, src8, a0, b0);
        if (kt2 + 1 < 12) pj_compute(a1, b1, wm, wn, ln, quad, acc);
    }

#pragma unroll
    for (int i = 0; i < 4; ++i) {
#pragma unroll
        for (int r = 0; r < 4; ++r) {
            int row_g = bm * 128 + wm * 64 + i * 16 + quad * 4 + r;
            if (row_g >= M_TOT) continue;
#pragma unroll
            for (int j = 0; j < 4; ++j) {
                int col_g = bn * 128 + wn * 64 + j * 16 + ln;
                out[(size_t)row_g * 768 + col_g] = acc[i][j][r] + pb[col_g];
            }
        }
    }
}

extern "C" void kernel_launch(void* const* d_in, const int* in_sizes, int n_in,
                              void* d_out, int out_size, void* d_ws, size_t ws_size,
                              hipStream_t stream) {
    const float* x     = (const float*)d_in[0];
    const float* qkvw  = (const float*)d_in[1];
    const float* qb    = (const float*)d_in[2];
    const float* vb    = (const float*)d_in[3];
    const float* rpb   = (const float*)d_in[4];
    const float* projw = (const float*)d_in[5];
    const float* pb    = (const float*)d_in[6];
    const int*   ridx  = (const int*)d_in[7];
    float* out = (float*)d_out;

    char* ws = (char*)d_ws;
    size_t off = 0;
    auto alloc = [&](size_t bytes) -> void* {
        void* p = ws + off;
        off = (off + bytes + 255) & ~(size_t)255;
        return p;
    };
    unsigned short* x_bf     = (unsigned short*)alloc((size_t)M_TOT * DIM_ * 2);
    unsigned short* qkvw_bf  = (unsigned short*)alloc((size_t)3 * DIM_ * DIM_ * 2);
    unsigned short* projw_bf = (unsigned short*)alloc((size_t)DIM_ * DIM_ * 2);
    float*          bias_h   = (float*)alloc((size_t)H_ * N_ * N_ * 4);
    unsigned short* att_ws   = (unsigned short*)alloc((size_t)(M_TOT + 64) * DIM_ * 2);
    (void)ws_size; (void)in_sizes; (void)n_in; (void)out_size;

    k_prep<<<1200, 256, 0, stream>>>(x, qkvw, projw, rpb, ridx,
                                     x_bf, qkvw_bf, projw_bf, bias_h);
    k_fused<<<768, 1024, 0, stream>>>(x_bf, qkvw_bf, qb, vb, bias_h, att_ws);
    k_proj<<<594, 256, 0, stream>>>(att_ws, projw_bf, pb, out);
}

// Round 3
// 220.087 us; speedup vs baseline: 1.9685x; 1.0100x over previous
//
#include <hip/hip_runtime.h>

// AttentionWindow (BEiT windowed attention), MI355X gfx950.
// B=64 N=197 DIM=768 H=12 hd=64. bf16 MFMA (16x16x32), fp32 softmax.
// R10: T3+T4 pipelining on R9's verified base. QKV loop: triple-buffered
//      staging, ONE raw s_barrier per phase, counted s_waitcnt vmcnt(3)
//      (never 0 mid-loop) -> prefetch depth 2, no full DMA drains.
//      k_proj: 1 barrier/phase (wait lands after a full compute phase).
//      Compute, epilogue, attention identical to R9 (absmax-verified).

#define B_    64
#define N_    197
#define DIM_  768
#define H_    12
#define HD_   64
#define M_TOT (B_ * N_)     // 12608

// fused LDS map (shorts): 3 staging buffers (A 13312 + B 12288 each) = 76800
// shorts = 153.6 KB. Q/K/VT (end 40960) overlays A0/A1/A2+B0-head after loop.
#define ST_A0   0
#define ST_A1   13312
#define ST_A2   26624
#define ST_B0   39936
#define ST_B1   52224
#define ST_B2   64512
#define OFF_Q   0            // 208 rows x 64, XOR-swizzled slots
#define OFF_K   13312        // 208 rows x 64
#define OFF_VT  26624        // 64 rows (d) x 224 (tok), group-swizzled
#define LDS_TOT 76800

typedef __attribute__((ext_vector_type(8))) short bf8;
typedef __attribute__((ext_vector_type(4))) float f4;

__device__ __forceinline__ unsigned short f2bf(float f) {
    unsigned u = __float_as_uint(f);
    u = (u + 0x7fffu + ((u >> 16) & 1u)) >> 16;
    return (unsigned short)u;
}

__device__ __forceinline__ void gl2lds16(const unsigned short* g, unsigned short* l) {
    __builtin_amdgcn_global_load_lds(
        (const __attribute__((address_space(1))) void*)g,
        (__attribute__((address_space(3))) void*)l, 16, 0, 0);
}

// Q/K LDS address (shorts): row-stride 64, 16B slot XOR-swizzled by row.
__device__ __forceinline__ int qkaddr(int row, int col) {
    return row * 64 + ((((col >> 3) ^ row) & 7) << 3) + (col & 7);
}
// VT LDS address (shorts): d-stride 224; 28 slots/row; XOR within slot groups
// (full 8-groups for s<24, the tail group of 4 uses a 2-bit XOR).
__device__ __forceinline__ int vtaddr(int d, int k) {
    int s = k >> 3;
    int s2 = (s < 24) ? ((s & 24) | ((s ^ d) & 7)) : (24 + ((s ^ d) & 3));
    return d * 224 + (s2 << 3) + (k & 7);
}

// ---------------- prep: fp32->bf16 converts, bias gather ----------------
__global__ void k_prep(const float* __restrict__ x, const float* __restrict__ qkvw,
                       const float* __restrict__ projw, const float* __restrict__ rpb,
                       const int* __restrict__ relidx,
                       unsigned short* __restrict__ x_bf, unsigned short* __restrict__ qkvw_bf,
                       unsigned short* __restrict__ projw_bf, float* __restrict__ bias_hqk) {
    const int T = gridDim.x * blockDim.x;
    const int tid = blockIdx.x * blockDim.x + threadIdx.x;
    for (int i = tid; i < M_TOT * DIM_; i += T) x_bf[i] = f2bf(x[i]);
    for (int i = tid; i < 3 * DIM_ * DIM_; i += T) qkvw_bf[i] = f2bf(qkvw[i]);
    for (int i = tid; i < DIM_ * DIM_; i += T) projw_bf[i] = f2bf(projw[i]);
    for (int i = tid; i < H_ * N_ * N_; i += T) {
        int h = i / (N_ * N_), qk = i - h * (N_ * N_);
        bias_hqk[i] = rpb[relidx[qk] * H_ + h];
    }
}

// ---------------- fused QKV + attention, one block (1024 thr) per (b,h) ----------------
__global__ __launch_bounds__(1024) void k_fused(const unsigned short* __restrict__ X,
                                                const unsigned short* __restrict__ Wqkv,
                                                const float* __restrict__ qb,
                                                const float* __restrict__ vbias,
                                                const float* __restrict__ bias_hqk,
                                                unsigned short* __restrict__ att_ws) {
    __shared__ unsigned short lds[LDS_TOT];

    const int t = threadIdx.x;                 // 0..1023
    const int w = t >> 6, lane = t & 63, ln = lane & 15, quad = lane >> 4;
    const int wm = w & 3, wn = w >> 2;         // (4 m-groups) x (4 n-groups)
    const int srl = lane >> 3;                 // local row 0..7 within 8-row group
    const int src8 = (lane & 7) ^ srl;         // stored-slot -> fetched-chunk XOR swizzle

    // XCD swizzle: gid%8 -> XCD; contiguous 8-b group per XCD keeps x in its L2
    const int gid = blockIdx.x;                // 0..767
    const int local = gid >> 3;                // 0..95
    const int b = (gid & 7) * 8 + (local & 7);
    const int h = local >> 3;                  // 0..11

    const unsigned short* xb = X + (size_t)b * 197 * 768;

    // ---- staging (BK=64): 50 DMA instrs/phase (26 A row-groups + 24 B), 16 waves
    // per-wave loads/phase: waves 0-1 -> 4, waves 2-15 -> 3 (vmcnt(3) is safe for both)
    auto stage = [&](int kt, int aOfs, int bOfs) {
#pragma unroll
        for (int i = 0; i < 4; ++i) {
            int idx = w + 16 * i;
            if (idx >= 50) break;              // wave-uniform
            if (idx < 26) {                    // A: token rows idx*8..+7
                int tok = 8 * idx + srl;
                if (tok > 196) tok = 196;      // clamp; pad rows discarded later
                gl2lds16(xb + (size_t)tok * 768 + kt * 64 + src8 * 8,
                         &lds[aOfs + idx * 512]);
            } else {                           // B: weight rows (3 passes x 64)
                int bb = idx - 26;
                int rr = 8 * bb + srl;         // 0..191
                gl2lds16(Wqkv + (size_t)((rr >> 6) * 768 + h * 64 + (rr & 63)) * 768
                              + kt * 64 + src8 * 8,
                         &lds[bOfs + bb * 512]);
            }
        }
    };

    f4 acc[4][3] = {};                         // [mi][tl]: wave tile = (4m x 4n), 12 tiles

    auto compute = [&](int aOfs, int bOfs) {
#pragma unroll
        for (int ks = 0; ks < 2; ++ks) {
            bf8 bfr[3];
#pragma unroll
            for (int tl = 0; tl < 3; ++tl) {
                int rr = (wn * 3 + tl) * 16 + ln;
                int slot = (ks * 4 + quad) ^ (rr & 7);
                bfr[tl] = *(const bf8*)&lds[bOfs + rr * 64 + slot * 8];
            }
#pragma unroll
            for (int mi = 0; mi < 4; ++mi) {
                int mt = wm + 4 * mi;
                if (mt >= 13) continue;        // wave-uniform (only wm>0, mi=3)
                int row = mt * 16 + ln;
                int slot = (ks * 4 + quad) ^ (row & 7);
                bf8 af = *(const bf8*)&lds[aOfs + row * 64 + slot * 8];
#pragma unroll
                for (int tl = 0; tl < 3; ++tl)
                    acc[mi][tl] = __builtin_amdgcn_mfma_f32_16x16x32_bf16(
                        af, bfr[tl], acc[mi][tl], 0, 0, 0);
            }
        }
    };

    // ---- T3+T4 pipelined K-loop: depth-2 prefetch, 1 raw barrier/phase,
    //      counted vmcnt (FIFO completion per m135 makes vmcnt(3) drain
    //      exactly this wave's phase-kt loads while kt+1's stay in flight).
    const int stA[3] = {ST_A0, ST_A1, ST_A2};
    const int stB[3] = {ST_B0, ST_B1, ST_B2};
    stage(0, ST_A0, ST_B0);
    stage(1, ST_A1, ST_B1);
#pragma unroll
    for (int kt = 0; kt < 12; ++kt) {
        if (kt < 11) { __asm__ __volatile__("s_waitcnt vmcnt(3)" ::: "memory"); }
        else         { __asm__ __volatile__("s_waitcnt vmcnt(0)" ::: "memory"); }
        __builtin_amdgcn_sched_barrier(0);
        __builtin_amdgcn_s_barrier();          // buf kt DMA-complete on all waves;
        __builtin_amdgcn_sched_barrier(0);     // buf (kt-1) readers all finished
        if (kt + 2 < 12) stage(kt + 2, stA[(kt + 2) % 3], stB[(kt + 2) % 3]);
        compute(stA[kt % 3], stB[kt % 3]);
    }
    __syncthreads();                           // staging dead: epilogue overlays it

    // ---- epilogue: C/D layout row=quad*4+r, col=ln (m89-verified) -> LDS Q/K/VT
#pragma unroll
    for (int tl = 0; tl < 3; ++tl) {
        int tn = wn * 3 + tl;
        int p = tn >> 2;                       // 0=Q 1=K 2=V
        int col = (tn & 3) * 16 + ln;          // 0..63 within the pass
        int d = h * 64 + col;
        float bj = (p == 0) ? qb[d] : (p == 2) ? vbias[d] : 0.0f;
#pragma unroll
        for (int mi = 0; mi < 4; ++mi) {
            int mt = wm + 4 * mi;
            if (mt >= 13) continue;
#pragma unroll
            for (int r = 0; r < 4; ++r) {
                int row = mt * 16 + quad * 4 + r;  // 0..207 (pad rows masked later)
                float v = acc[mi][tl][r];
                if (p == 0)      lds[OFF_Q + qkaddr(row, col)] = f2bf((v + bj) * 0.125f);
                else if (p == 1) lds[OFF_K + qkaddr(row, col)] = f2bf(v);
                else             lds[OFF_VT + vtaddr(col, row)] = f2bf(v + bj);
            }
        }
    }
    // zero VT K-pad cols 208..223 (cols 197..207 hold finite clamped data)
    for (int idx = t; idx < 64 * 16; idx += 1024) {
        int d = idx >> 4, k = 208 + (idx & 15);
        lds[OFF_VT + vtaddr(d, k)] = 0;
    }
    __syncthreads();

    // ---- attention (Q/K/VT in LDS, P fully in-register), 16 waves, 13 m-tiles ----
    const float* bp = bias_hqk + (size_t)h * 197 * 197;

    for (int mt = w; mt < 13; mt += 16) {
        // Q as B-operand (hoisted): lane ln supplies q-row mt*16+ln
        bf8 qa[2];
#pragma unroll
        for (int ks = 0; ks < 2; ++ks)
            qa[ks] = *(const bf8*)&lds[OFF_Q + qkaddr(mt * 16 + ln, ks * 32 + quad * 8)];

        // swapped QK: S^T[k][q];  lane(ln,quad) reg r holds S[q=mt*16+ln][k=nt*16+quad*4+r]
        f4 sacc[13];
#pragma unroll
        for (int nt = 0; nt < 13; ++nt) sacc[nt] = (f4){0.f, 0.f, 0.f, 0.f};
        __builtin_amdgcn_s_setprio(1);
#pragma unroll
        for (int nt = 0; nt < 13; ++nt) {
#pragma unroll
            for (int ks = 0; ks < 2; ++ks) {
                bf8 ka = *(const bf8*)&lds[OFF_K + qkaddr(nt * 16 + ln, ks * 32 + quad * 8)];
                sacc[nt] = __builtin_amdgcn_mfma_f32_16x16x32_bf16(ka, qa[ks], sacc[nt], 0, 0, 0);
            }
        }
        __builtin_amdgcn_s_setprio(0);

        // softmax: row is lane-local across (nt,r); cross-lane only over quad (2 shfl)
        int qg = mt * 16 + ln;
        const float* brow = bp + (size_t)(qg < 197 ? qg : 196) * 197;
        float mx = -3.0e38f;
#pragma unroll
        for (int nt = 0; nt < 13; ++nt)
#pragma unroll
            for (int r = 0; r < 4; ++r) {
                int kg = nt * 16 + quad * 4 + r;
                float s = (kg < 197) ? (sacc[nt][r] + brow[kg]) : -3.0e38f;
                sacc[nt][r] = s;
                mx = fmaxf(mx, s);
            }
        mx = fmaxf(mx, __shfl_xor(mx, 16, 64));
        mx = fmaxf(mx, __shfl_xor(mx, 32, 64));
        float sum = 0.f;
#pragma unroll
        for (int nt = 0; nt < 13; ++nt)
#pragma unroll
            for (int r = 0; r < 4; ++r) {
                float pv = __expf(sacc[nt][r] - mx);
                sacc[nt][r] = pv;
                sum += pv;
            }
        sum += __shfl_xor(sum, 16, 64);
        sum += __shfl_xor(sum, 32, 64);
        float inv = 1.0f / sum;

        // pack normalized P to bf16 pairs: pk[nt][0]=(r0,r1), pk[nt][1]=(r2,r3)
        unsigned pk[14][2];
#pragma unroll
        for (int nt = 0; nt < 13; ++nt) {
            pk[nt][0] = (unsigned)f2bf(sacc[nt][0] * inv) |
                        ((unsigned)f2bf(sacc[nt][1] * inv) << 16);
            pk[nt][1] = (unsigned)f2bf(sacc[nt][2] * inv) |
                        ((unsigned)f2bf(sacc[nt][3] * inv) << 16);
        }
        pk[13][0] = 0; pk[13][1] = 0;          // K-pad 208..223 -> P = 0

        // PV: A-frag (lane ln = q-row ln, k-chunk = quad*8) built by ds_bpermute:
        // target quad q_t takes k=32ks+8q_t+[0..7] from source lanes
        // (ln + 32*(q_t&1)) and (+16), register set nt = 2ks + (q_t>>1).
        const int sA = (((lane & 15) | ((lane & 16) << 1)) << 2);
        const int sB = sA + 64;
        const bool hi = (lane & 32) != 0;
        f4 o[4];
#pragma unroll
        for (int j = 0; j < 4; ++j) o[j] = (f4){0.f, 0.f, 0.f, 0.f};
#pragma unroll
        for (int ks = 0; ks < 7; ++ks) {
            int b0 = __builtin_amdgcn_ds_bpermute(sA, (int)pk[2 * ks][0]);
            int b1 = __builtin_amdgcn_ds_bpermute(sA, (int)pk[2 * ks][1]);
            int b2 = __builtin_amdgcn_ds_bpermute(sB, (int)pk[2 * ks][0]);
            int b3 = __builtin_amdgcn_ds_bpermute(sB, (int)pk[2 * ks][1]);
            int c0 = __builtin_amdgcn_ds_bpermute(sA, (int)pk[2 * ks + 1][0]);
            int c1 = __builtin_amdgcn_ds_bpermute(sA, (int)pk[2 * ks + 1][1]);
            int c2 = __builtin_amdgcn_ds_bpermute(sB, (int)pk[2 * ks + 1][0]);
            int c3 = __builtin_amdgcn_ds_bpermute(sB, (int)pk[2 * ks + 1][1]);
            union { int u[4]; bf8 v; } uu;
            uu.u[0] = hi ? c0 : b0;
            uu.u[1] = hi ? c1 : b1;
            uu.u[2] = hi ? c2 : b2;
            uu.u[3] = hi ? c3 : b3;
            __builtin_amdgcn_s_setprio(1);
#pragma unroll
            for (int j = 0; j < 4; ++j) {
                bf8 vf = *(const bf8*)&lds[OFF_VT + vtaddr(j * 16 + ln, ks * 32 + quad * 8)];
                o[j] = __builtin_amdgcn_mfma_f32_16x16x32_bf16(uu.v, vf, o[j], 0, 0, 0);
            }
            __builtin_amdgcn_s_setprio(0);
        }
#pragma unroll
        for (int j = 0; j < 4; ++j)
#pragma unroll
            for (int r = 0; r < 4; ++r) {
                int tok = mt * 16 + quad * 4 + r;
                if (tok < 197)
                    att_ws[((size_t)b * 197 + tok) * 768 + h * 64 + j * 16 + ln] = f2bf(o[j][r]);
            }
    }
}

// ---------------- proj GEMM: (12608x768) @ (768x768)^T + bias -> fp32 out ----------------
__device__ __forceinline__ void pj_stage(const unsigned short* __restrict__ A,
                                         const unsigned short* __restrict__ Bm,
                                         int bm, int bn, int kt, int w, int rsub, int src8,
                                         unsigned short* a_l, unsigned short* b_l) {
#pragma unroll
    for (int c = 0; c < 4; ++c) {
        int rb = w * 32 + c * 8;
        int gr = bm * 128 + rb + rsub;
        if (gr > M_TOT - 1) gr = M_TOT - 1;
        gl2lds16(A + (size_t)gr * 768 + kt * 64 + (src8 << 3), &a_l[rb * 64]);
        int gc = bn * 128 + rb + rsub;      // < 768
        gl2lds16(Bm + (size_t)gc * 768 + kt * 64 + (src8 << 3), &b_l[rb * 64]);
    }
}

__device__ __forceinline__ void pj_compute(const unsigned short* a_l, const unsigned short* b_l,
                                           int wm, int wn, int ln, int quad, f4 (*acc)[4]) {
#pragma unroll
    for (int ks = 0; ks < 2; ++ks) {
        bf8 af[4], bfr[4];
#pragma unroll
        for (int i = 0; i < 4; ++i)
            af[i] = *(const bf8*)&a_l[((wm * 64 + i * 16 + ln) << 6) +
                                      ((((ks << 2) + quad) ^ (ln & 7)) << 3)];
#pragma unroll
        for (int j = 0; j < 4; ++j)
            bfr[j] = *(const bf8*)&b_l[((wn * 64 + j * 16 + ln) << 6) +
                                       ((((ks << 2) + quad) ^ (ln & 7)) << 3)];
#pragma unroll
        for (int i = 0; i < 4; ++i)
#pragma unroll
            for (int j = 0; j < 4; ++j)
                acc[i][j] = __builtin_amdgcn_mfma_f32_16x16x32_bf16(af[i], bfr[j], acc[i][j], 0, 0, 0);
    }
}

__global__ __launch_bounds__(256) void k_proj(const unsigned short* __restrict__ A,
                                              const unsigned short* __restrict__ Bm,
                                              const float* __restrict__ pb,
                                              float* __restrict__ out) {
    __shared__ unsigned short a0[128 * 64], a1[128 * 64];
    __shared__ unsigned short b0[128 * 64], b1[128 * 64];
    const int t = threadIdx.x;
    const int w = t >> 6, lane = t & 63, ln = lane & 15, quad = lane >> 4;
    const int wm = w & 1, wn = w >> 1;

    const int gid = blockIdx.x;                 // panels: 8 bm x 6 bn = 48
    const int panel = gid / 48, rem = gid - panel * 48;
    const int pm0 = panel * 8;
    const int psz = (99 - pm0 < 8) ? (99 - pm0) : 8;
    const int bm = pm0 + rem % psz;
    const int bn = rem / psz;

    const int rsub = lane >> 3;
    const int src8 = (lane & 7) ^ rsub;

    f4 acc[4][4] = {};

    // 1 barrier/phase: [wait own buf-kt DMA][barrier][stage kt+1][compute kt]
    // stage(kt+1) overwrites buf[(kt-1)&1], whose readers all passed the barrier.
    pj_stage(A, Bm, bm, bn, 0, w, rsub, src8, a0, b0);
#pragma unroll
    for (int kt = 0; kt < 12; ++kt) {
        __asm__ __volatile__("s_waitcnt vmcnt(0)" ::: "memory");
        __builtin_amdgcn_sched_barrier(0);
        __builtin_amdgcn_s_barrier();
        __builtin_amdgcn_sched_barrier(0);
        if (kt + 1 < 12) pj_stage(A, Bm, bm, bn, kt + 1, w, rsub, src8,
                                  (kt & 1) ? a0 : a1, (kt & 1) ? b0 : b1);
        pj_compute((kt & 1) ? a1 : a0, (kt & 1) ? b1 : b0, wm, wn, ln, quad, acc);
    }

#pragma unroll
    for (int i = 0; i < 4; ++i) {
#pragma unroll
        for (int r = 0; r < 4; ++r) {
            int row_g = bm * 128 + wm * 64 + i * 16 + quad * 4 + r;
            if (row_g >= M_TOT) continue;
#pragma unroll
            for (int j = 0; j < 4; ++j) {
                int col_g = bn * 128 + wn * 64 + j * 16 + ln;
                out[(size_t)row_g * 768 + col_g] = acc[i][j][r] + pb[col_g];
            }
        }
    }
}

extern "C" void kernel_launch(void* const* d_in, const int* in_sizes, int n_in,
                              void* d_out, int out_size, void* d_ws, size_t ws_size,
                              hipStream_t stream) {
    const float* x     = (const float*)d_in[0];
    const float* qkvw  = (const float*)d_in[1];
    const float* qb    = (const float*)d_in[2];
    const float* vb    = (const float*)d_in[3];
    const float* rpb   = (const float*)d_in[4];
    const float* projw = (const float*)d_in[5];
    const float* pb    = (const float*)d_in[6];
    const int*   ridx  = (const int*)d_in[7];
    float* out = (float*)d_out;

    char* ws = (char*)d_ws;
    size_t off = 0;
    auto alloc = [&](size_t bytes) -> void* {
        void* p = ws + off;
        off = (off + bytes + 255) & ~(size_t)255;
        return p;
    };
    unsigned short* x_bf     = (unsigned short*)alloc((size_t)M_TOT * DIM_ * 2);
    unsigned short* qkvw_bf  = (unsigned short*)alloc((size_t)3 * DIM_ * DIM_ * 2);
    unsigned short* projw_bf = (unsigned short*)alloc((size_t)DIM_ * DIM_ * 2);
    float*          bias_h   = (float*)alloc((size_t)H_ * N_ * N_ * 4);
    unsigned short* att_ws   = (unsigned short*)alloc((size_t)(M_TOT + 64) * DIM_ * 2);
    (void)ws_size; (void)in_sizes; (void)n_in; (void)out_size;

    k_prep<<<1200, 256, 0, stream>>>(x, qkvw, projw, rpb, ridx,
                                     x_bf, qkvw_bf, projw_bf, bias_h);
    k_fused<<<768, 1024, 0, stream>>>(x_bf, qkvw_bf, qb, vb, bias_h, att_ws);
    k_proj<<<594, 256, 0, stream>>>(att_ws, projw_bf, pb, out);
}

// Round 4
// 211.545 us; speedup vs baseline: 2.0479x; 1.0404x over previous
//
#include <hip/hip_runtime.h>

// AttentionWindow (BEiT windowed attention), MI355X gfx950.
// B=64 N=197 DIM=768 H=12 hd=64. bf16 MFMA (16x16x32), fp32 softmax.
// R11: SIMD load-balance on R10's verified base.
//      - QKV partition wm=w>>2, wn=w&3: waves land on SIMD w%4, so each SIMD
//        now hosts wm {0,1,2,3} (78 MFMA-issues/SIMD/phase, was 96 on SIMD0).
//      - stage() DMA index reversed: the 4-load waves are now the light
//        (wm=3) compute waves.
//      - s_setprio(1) around QKV MFMA cluster (T5; role-split exists now).
//      - k_prep vectorized: float4 -> ushort4 (G13).
//      Pipeline structure (3-buf, 1 barrier/phase, counted vmcnt) unchanged.

#define B_    64
#define N_    197
#define DIM_  768
#define H_    12
#define HD_   64
#define M_TOT (B_ * N_)     // 12608

// fused LDS map (shorts): 3 staging buffers (A 13312 + B 12288 each) = 76800
// shorts = 153.6 KB. Q/K/VT (end 40960) overlays A0/A1/A2+B0-head after loop.
#define ST_A0   0
#define ST_A1   13312
#define ST_A2   26624
#define ST_B0   39936
#define ST_B1   52224
#define ST_B2   64512
#define OFF_Q   0            // 208 rows x 64, XOR-swizzled slots
#define OFF_K   13312        // 208 rows x 64
#define OFF_VT  26624        // 64 rows (d) x 224 (tok), group-swizzled
#define LDS_TOT 76800

typedef __attribute__((ext_vector_type(8))) short bf8;
typedef __attribute__((ext_vector_type(4))) float f4;
typedef __attribute__((ext_vector_type(4))) unsigned short us4;

__device__ __forceinline__ unsigned short f2bf(float f) {
    unsigned u = __float_as_uint(f);
    u = (u + 0x7fffu + ((u >> 16) & 1u)) >> 16;
    return (unsigned short)u;
}

__device__ __forceinline__ void gl2lds16(const unsigned short* g, unsigned short* l) {
    __builtin_amdgcn_global_load_lds(
        (const __attribute__((address_space(1))) void*)g,
        (__attribute__((address_space(3))) void*)l, 16, 0, 0);
}

// Q/K LDS address (shorts): row-stride 64, 16B slot XOR-swizzled by row.
__device__ __forceinline__ int qkaddr(int row, int col) {
    return row * 64 + ((((col >> 3) ^ row) & 7) << 3) + (col & 7);
}
// VT LDS address (shorts): d-stride 224; 28 slots/row; XOR within slot groups
// (full 8-groups for s<24, the tail group of 4 uses a 2-bit XOR).
__device__ __forceinline__ int vtaddr(int d, int k) {
    int s = k >> 3;
    int s2 = (s < 24) ? ((s & 24) | ((s ^ d) & 7)) : (24 + ((s ^ d) & 3));
    return d * 224 + (s2 << 3) + (k & 7);
}

// ---------------- prep: fp32->bf16 converts (vectorized), bias gather ----------------
__global__ void k_prep(const float* __restrict__ x, const float* __restrict__ qkvw,
                       const float* __restrict__ projw, const float* __restrict__ rpb,
                       const int* __restrict__ relidx,
                       unsigned short* __restrict__ x_bf, unsigned short* __restrict__ qkvw_bf,
                       unsigned short* __restrict__ projw_bf, float* __restrict__ bias_hqk) {
    const int T = gridDim.x * blockDim.x;
    const int tid = blockIdx.x * blockDim.x + threadIdx.x;
    // all three bulk arrays have elem counts divisible by 4
    for (int i = tid; i < M_TOT * DIM_ / 4; i += T) {
        float4 v = ((const float4*)x)[i];
        us4 o = {f2bf(v.x), f2bf(v.y), f2bf(v.z), f2bf(v.w)};
        ((us4*)x_bf)[i] = o;
    }
    for (int i = tid; i < 3 * DIM_ * DIM_ / 4; i += T) {
        float4 v = ((const float4*)qkvw)[i];
        us4 o = {f2bf(v.x), f2bf(v.y), f2bf(v.z), f2bf(v.w)};
        ((us4*)qkvw_bf)[i] = o;
    }
    for (int i = tid; i < DIM_ * DIM_ / 4; i += T) {
        float4 v = ((const float4*)projw)[i];
        us4 o = {f2bf(v.x), f2bf(v.y), f2bf(v.z), f2bf(v.w)};
        ((us4*)projw_bf)[i] = o;
    }
    for (int i = tid; i < H_ * N_ * N_; i += T) {
        int h = i / (N_ * N_), qk = i - h * (N_ * N_);
        bias_hqk[i] = rpb[relidx[qk] * H_ + h];
    }
}

// ---------------- fused QKV + attention, one block (1024 thr) per (b,h) ----------------
__global__ __launch_bounds__(1024) void k_fused(const unsigned short* __restrict__ X,
                                                const unsigned short* __restrict__ Wqkv,
                                                const float* __restrict__ qb,
                                                const float* __restrict__ vbias,
                                                const float* __restrict__ bias_hqk,
                                                unsigned short* __restrict__ att_ws) {
    __shared__ unsigned short lds[LDS_TOT];

    const int t = threadIdx.x;                 // 0..1023
    const int w = t >> 6, lane = t & 63, ln = lane & 15, quad = lane >> 4;
    const int wm = w >> 2, wn = w & 3;         // SIMD-balanced: SIMD w%4 hosts wm 0..3
    const int srl = lane >> 3;                 // local row 0..7 within 8-row group
    const int src8 = (lane & 7) ^ srl;         // stored-slot -> fetched-chunk XOR swizzle

    // XCD swizzle: gid%8 -> XCD; contiguous 8-b group per XCD keeps x in its L2
    const int gid = blockIdx.x;                // 0..767
    const int local = gid >> 3;                // 0..95
    const int b = (gid & 7) * 8 + (local & 7);
    const int h = local >> 3;                  // 0..11

    const unsigned short* xb = X + (size_t)b * 197 * 768;

    // ---- staging (BK=64): 50 DMA instrs/phase (26 A row-groups + 24 B), 16 waves
    // reversed index: the 4-load waves (14,15) carry the lightest MFMA load (wm=3)
    auto stage = [&](int kt, int aOfs, int bOfs) {
#pragma unroll
        for (int i = 0; i < 4; ++i) {
            int idx = (15 - w) + 16 * i;
            if (idx >= 50) break;              // wave-uniform
            if (idx < 26) {                    // A: token rows idx*8..+7
                int tok = 8 * idx + srl;
                if (tok > 196) tok = 196;      // clamp; pad rows discarded later
                gl2lds16(xb + (size_t)tok * 768 + kt * 64 + src8 * 8,
                         &lds[aOfs + idx * 512]);
            } else {                           // B: weight rows (3 passes x 64)
                int bb = idx - 26;
                int rr = 8 * bb + srl;         // 0..191
                gl2lds16(Wqkv + (size_t)((rr >> 6) * 768 + h * 64 + (rr & 63)) * 768
                              + kt * 64 + src8 * 8,
                         &lds[bOfs + bb * 512]);
            }
        }
    };

    f4 acc[4][3] = {};                         // [mi][tl]: wave tile = (4m x 4n), 12 tiles

    auto compute = [&](int aOfs, int bOfs) {
#pragma unroll
        for (int ks = 0; ks < 2; ++ks) {
            bf8 bfr[3];
#pragma unroll
            for (int tl = 0; tl < 3; ++tl) {
                int rr = (wn * 3 + tl) * 16 + ln;
                int slot = (ks * 4 + quad) ^ (rr & 7);
                bfr[tl] = *(const bf8*)&lds[bOfs + rr * 64 + slot * 8];
            }
            __builtin_amdgcn_s_setprio(1);
#pragma unroll
            for (int mi = 0; mi < 4; ++mi) {
                int mt = wm + 4 * mi;
                if (mt >= 13) continue;        // wave-uniform (only wm>0, mi=3)
                int row = mt * 16 + ln;
                int slot = (ks * 4 + quad) ^ (row & 7);
                bf8 af = *(const bf8*)&lds[aOfs + row * 64 + slot * 8];
#pragma unroll
                for (int tl = 0; tl < 3; ++tl)
                    acc[mi][tl] = __builtin_amdgcn_mfma_f32_16x16x32_bf16(
                        af, bfr[tl], acc[mi][tl], 0, 0, 0);
            }
            __builtin_amdgcn_s_setprio(0);
        }
    };

    // ---- T3+T4 pipelined K-loop: depth-2 prefetch, 1 raw barrier/phase,
    //      counted vmcnt (FIFO completion per m135 makes vmcnt(3) drain
    //      exactly this wave's phase-kt loads while kt+1's stay in flight).
    const int stA[3] = {ST_A0, ST_A1, ST_A2};
    const int stB[3] = {ST_B0, ST_B1, ST_B2};
    stage(0, ST_A0, ST_B0);
    stage(1, ST_A1, ST_B1);
#pragma unroll
    for (int kt = 0; kt < 12; ++kt) {
        if (kt < 11) { __asm__ __volatile__("s_waitcnt vmcnt(3)" ::: "memory"); }
        else         { __asm__ __volatile__("s_waitcnt vmcnt(0)" ::: "memory"); }
        __builtin_amdgcn_sched_barrier(0);
        __builtin_amdgcn_s_barrier();          // buf kt DMA-complete on all waves;
        __builtin_amdgcn_sched_barrier(0);     // buf (kt-1) readers all finished
        if (kt + 2 < 12) stage(kt + 2, stA[(kt + 2) % 3], stB[(kt + 2) % 3]);
        compute(stA[kt % 3], stB[kt % 3]);
    }
    __syncthreads();                           // staging dead: epilogue overlays it

    // ---- epilogue: C/D layout row=quad*4+r, col=ln (m89-verified) -> LDS Q/K/VT
#pragma unroll
    for (int tl = 0; tl < 3; ++tl) {
        int tn = wn * 3 + tl;
        int p = tn >> 2;                       // 0=Q 1=K 2=V
        int col = (tn & 3) * 16 + ln;          // 0..63 within the pass
        int d = h * 64 + col;
        float bj = (p == 0) ? qb[d] : (p == 2) ? vbias[d] : 0.0f;
#pragma unroll
        for (int mi = 0; mi < 4; ++mi) {
            int mt = wm + 4 * mi;
            if (mt >= 13) continue;
#pragma unroll
            for (int r = 0; r < 4; ++r) {
                int row = mt * 16 + quad * 4 + r;  // 0..207 (pad rows masked later)
                float v = acc[mi][tl][r];
                if (p == 0)      lds[OFF_Q + qkaddr(row, col)] = f2bf((v + bj) * 0.125f);
                else if (p == 1) lds[OFF_K + qkaddr(row, col)] = f2bf(v);
                else             lds[OFF_VT + vtaddr(col, row)] = f2bf(v + bj);
            }
        }
    }
    // zero VT K-pad cols 208..223 (cols 197..207 hold finite clamped data)
    for (int idx = t; idx < 64 * 16; idx += 1024) {
        int d = idx >> 4, k = 208 + (idx & 15);
        lds[OFF_VT + vtaddr(d, k)] = 0;
    }
    __syncthreads();

    // ---- attention (Q/K/VT in LDS, P fully in-register), 16 waves, 13 m-tiles ----
    const float* bp = bias_hqk + (size_t)h * 197 * 197;

    for (int mt = w; mt < 13; mt += 16) {
        // Q as B-operand (hoisted): lane ln supplies q-row mt*16+ln
        bf8 qa[2];
#pragma unroll
        for (int ks = 0; ks < 2; ++ks)
            qa[ks] = *(const bf8*)&lds[OFF_Q + qkaddr(mt * 16 + ln, ks * 32 + quad * 8)];

        // swapped QK: S^T[k][q];  lane(ln,quad) reg r holds S[q=mt*16+ln][k=nt*16+quad*4+r]
        f4 sacc[13];
#pragma unroll
        for (int nt = 0; nt < 13; ++nt) sacc[nt] = (f4){0.f, 0.f, 0.f, 0.f};
        __builtin_amdgcn_s_setprio(1);
#pragma unroll
        for (int nt = 0; nt < 13; ++nt) {
#pragma unroll
            for (int ks = 0; ks < 2; ++ks) {
                bf8 ka = *(const bf8*)&lds[OFF_K + qkaddr(nt * 16 + ln, ks * 32 + quad * 8)];
                sacc[nt] = __builtin_amdgcn_mfma_f32_16x16x32_bf16(ka, qa[ks], sacc[nt], 0, 0, 0);
            }
        }
        __builtin_amdgcn_s_setprio(0);

        // softmax: row is lane-local across (nt,r); cross-lane only over quad (2 shfl)
        int qg = mt * 16 + ln;
        const float* brow = bp + (size_t)(qg < 197 ? qg : 196) * 197;
        float mx = -3.0e38f;
#pragma unroll
        for (int nt = 0; nt < 13; ++nt)
#pragma unroll
            for (int r = 0; r < 4; ++r) {
                int kg = nt * 16 + quad * 4 + r;
                float s = (kg < 197) ? (sacc[nt][r] + brow[kg]) : -3.0e38f;
                sacc[nt][r] = s;
                mx = fmaxf(mx, s);
            }
        mx = fmaxf(mx, __shfl_xor(mx, 16, 64));
        mx = fmaxf(mx, __shfl_xor(mx, 32, 64));
        float sum = 0.f;
#pragma unroll
        for (int nt = 0; nt < 13; ++nt)
#pragma unroll
            for (int r = 0; r < 4; ++r) {
                float pv = __expf(sacc[nt][r] - mx);
                sacc[nt][r] = pv;
                sum += pv;
            }
        sum += __shfl_xor(sum, 16, 64);
        sum += __shfl_xor(sum, 32, 64);
        float inv = 1.0f / sum;

        // pack normalized P to bf16 pairs: pk[nt][0]=(r0,r1), pk[nt][1]=(r2,r3)
        unsigned pk[14][2];
#pragma unroll
        for (int nt = 0; nt < 13; ++nt) {
            pk[nt][0] = (unsigned)f2bf(sacc[nt][0] * inv) |
                        ((unsigned)f2bf(sacc[nt][1] * inv) << 16);
            pk[nt][1] = (unsigned)f2bf(sacc[nt][2] * inv) |
                        ((unsigned)f2bf(sacc[nt][3] * inv) << 16);
        }
        pk[13][0] = 0; pk[13][1] = 0;          // K-pad 208..223 -> P = 0

        // PV: A-frag (lane ln = q-row ln, k-chunk = quad*8) built by ds_bpermute:
        // target quad q_t takes k=32ks+8q_t+[0..7] from source lanes
        // (ln + 32*(q_t&1)) and (+16), register set nt = 2ks + (q_t>>1).
        const int sA = (((lane & 15) | ((lane & 16) << 1)) << 2);
        const int sB = sA + 64;
        const bool hi = (lane & 32) != 0;
        f4 o[4];
#pragma unroll
        for (int j = 0; j < 4; ++j) o[j] = (f4){0.f, 0.f, 0.f, 0.f};
#pragma unroll
        for (int ks = 0; ks < 7; ++ks) {
            int b0 = __builtin_amdgcn_ds_bpermute(sA, (int)pk[2 * ks][0]);
            int b1 = __builtin_amdgcn_ds_bpermute(sA, (int)pk[2 * ks][1]);
            int b2 = __builtin_amdgcn_ds_bpermute(sB, (int)pk[2 * ks][0]);
            int b3 = __builtin_amdgcn_ds_bpermute(sB, (int)pk[2 * ks][1]);
            int c0 = __builtin_amdgcn_ds_bpermute(sA, (int)pk[2 * ks + 1][0]);
            int c1 = __builtin_amdgcn_ds_bpermute(sA, (int)pk[2 * ks + 1][1]);
            int c2 = __builtin_amdgcn_ds_bpermute(sB, (int)pk[2 * ks + 1][0]);
            int c3 = __builtin_amdgcn_ds_bpermute(sB, (int)pk[2 * ks + 1][1]);
            union { int u[4]; bf8 v; } uu;
            uu.u[0] = hi ? c0 : b0;
            uu.u[1] = hi ? c1 : b1;
            uu.u[2] = hi ? c2 : b2;
            uu.u[3] = hi ? c3 : b3;
            __builtin_amdgcn_s_setprio(1);
#pragma unroll
            for (int j = 0; j < 4; ++j) {
                bf8 vf = *(const bf8*)&lds[OFF_VT + vtaddr(j * 16 + ln, ks * 32 + quad * 8)];
                o[j] = __builtin_amdgcn_mfma_f32_16x16x32_bf16(uu.v, vf, o[j], 0, 0, 0);
            }
            __builtin_amdgcn_s_setprio(0);
        }
#pragma unroll
        for (int j = 0; j < 4; ++j)
#pragma unroll
            for (int r = 0; r < 4; ++r) {
                int tok = mt * 16 + quad * 4 + r;
                if (tok < 197)
                    att_ws[((size_t)b * 197 + tok) * 768 + h * 64 + j * 16 + ln] = f2bf(o[j][r]);
            }
    }
}

// ---------------- proj GEMM: (12608x768) @ (768x768)^T + bias -> fp32 out ----------------
__device__ __forceinline__ void pj_stage(const unsigned short* __restrict__ A,
                                         const unsigned short* __restrict__ Bm,
                                         int bm, int bn, int kt, int w, int rsub, int src8,
                                         unsigned short* a_l, unsigned short* b_l) {
#pragma unroll
    for (int c = 0; c < 4; ++c) {
        int rb = w * 32 + c * 8;
        int gr = bm * 128 + rb + rsub;
        if (gr > M_TOT - 1) gr = M_TOT - 1;
        gl2lds16(A + (size_t)gr * 768 + kt * 64 + (src8 << 3), &a_l[rb * 64]);
        int gc = bn * 128 + rb + rsub;      // < 768
        gl2lds16(Bm + (size_t)gc * 768 + kt * 64 + (src8 << 3), &b_l[rb * 64]);
    }
}

__device__ __forceinline__ void pj_compute(const unsigned short* a_l, const unsigned short* b_l,
                                           int wm, int wn, int ln, int quad, f4 (*acc)[4]) {
#pragma unroll
    for (int ks = 0; ks < 2; ++ks) {
        bf8 af[4], bfr[4];
#pragma unroll
        for (int i = 0; i < 4; ++i)
            af[i] = *(const bf8*)&a_l[((wm * 64 + i * 16 + ln) << 6) +
                                      ((((ks << 2) + quad) ^ (ln & 7)) << 3)];
#pragma unroll
        for (int j = 0; j < 4; ++j)
            bfr[j] = *(const bf8*)&b_l[((wn * 64 + j * 16 + ln) << 6) +
                                       ((((ks << 2) + quad) ^ (ln & 7)) << 3)];
#pragma unroll
        for (int i = 0; i < 4; ++i)
#pragma unroll
            for (int j = 0; j < 4; ++j)
                acc[i][j] = __builtin_amdgcn_mfma_f32_16x16x32_bf16(af[i], bfr[j], acc[i][j], 0, 0, 0);
    }
}

__global__ __launch_bounds__(256) void k_proj(const unsigned short* __restrict__ A,
                                              const unsigned short* __restrict__ Bm,
                                              const float* __restrict__ pb,
                                              float* __restrict__ out) {
    __shared__ unsigned short a0[128 * 64], a1[128 * 64];
    __shared__ unsigned short b0[128 * 64], b1[128 * 64];
    const int t = threadIdx.x;
    const int w = t >> 6, lane = t & 63, ln = lane & 15, quad = lane >> 4;
    const int wm = w & 1, wn = w >> 1;

    const int gid = blockIdx.x;                 // panels: 8 bm x 6 bn = 48
    const int panel = gid / 48, rem = gid - panel * 48;
    const int pm0 = panel * 8;
    const int psz = (99 - pm0 < 8) ? (99 - pm0) : 8;
    const int bm = pm0 + rem % psz;
    const int bn = rem / psz;

    const int rsub = lane >> 3;
    const int src8 = (lane & 7) ^ rsub;

    f4 acc[4][4] = {};

    // 1 barrier/phase: [wait own buf-kt DMA][barrier][stage kt+1][compute kt]
    // stage(kt+1) overwrites buf[(kt-1)&1], whose readers all passed the barrier.
    pj_stage(A, Bm, bm, bn, 0, w, rsub, src8, a0, b0);
#pragma unroll
    for (int kt = 0; kt < 12; ++kt) {
        __asm__ __volatile__("s_waitcnt vmcnt(0)" ::: "memory");
        __builtin_amdgcn_sched_barrier(0);
        __builtin_amdgcn_s_barrier();
        __builtin_amdgcn_sched_barrier(0);
        if (kt + 1 < 12) pj_stage(A, Bm, bm, bn, kt + 1, w, rsub, src8,
                                  (kt & 1) ? a0 : a1, (kt & 1) ? b0 : b1);
        pj_compute((kt & 1) ? a1 : a0, (kt & 1) ? b1 : b0, wm, wn, ln, quad, acc);
    }

#pragma unroll
    for (int i = 0; i < 4; ++i) {
#pragma unroll
        for (int r = 0; r < 4; ++r) {
            int row_g = bm * 128 + wm * 64 + i * 16 + quad * 4 + r;
            if (row_g >= M_TOT) continue;
#pragma unroll
            for (int j = 0; j < 4; ++j) {
                int col_g = bn * 128 + wn * 64 + j * 16 + ln;
                out[(size_t)row_g * 768 + col_g] = acc[i][j][r] + pb[col_g];
            }
        }
    }
}

extern "C" void kernel_launch(void* const* d_in, const int* in_sizes, int n_in,
                              void* d_out, int out_size, void* d_ws, size_t ws_size,
                              hipStream_t stream) {
    const float* x     = (const float*)d_in[0];
    const float* qkvw  = (const float*)d_in[1];
    const float* qb    = (const float*)d_in[2];
    const float* vb    = (const float*)d_in[3];
    const float* rpb   = (const float*)d_in[4];
    const float* projw = (const float*)d_in[5];
    const float* pb    = (const float*)d_in[6];
    const int*   ridx  = (const int*)d_in[7];
    float* out = (float*)d_out;

    char* ws = (char*)d_ws;
    size_t off = 0;
    auto alloc = [&](size_t bytes) -> void* {
        void* p = ws + off;
        off = (off + bytes + 255) & ~(size_t)255;
        return p;
    };
    unsigned short* x_bf     = (unsigned short*)alloc((size_t)M_TOT * DIM_ * 2);
    unsigned short* qkvw_bf  = (unsigned short*)alloc((size_t)3 * DIM_ * DIM_ * 2);
    unsigned short* projw_bf = (unsigned short*)alloc((size_t)DIM_ * DIM_ * 2);
    float*          bias_h   = (float*)alloc((size_t)H_ * N_ * N_ * 4);
    unsigned short* att_ws   = (unsigned short*)alloc((size_t)(M_TOT + 64) * DIM_ * 2);
    (void)ws_size; (void)in_sizes; (void)n_in; (void)out_size;

    k_prep<<<1200, 256, 0, stream>>>(x, qkvw, projw, rpb, ridx,
                                     x_bf, qkvw_bf, projw_bf, bias_h);
    k_fused<<<768, 1024, 0, stream>>>(x_bf, qkvw_bf, qb, vb, bias_h, att_ws);
    k_proj<<<594, 256, 0, stream>>>(att_ws, projw_bf, pb, out);
}

// Round 5
// 210.975 us; speedup vs baseline: 2.0535x; 1.0027x over previous
//
#include <hip/hip_runtime.h>

// AttentionWindow (BEiT windowed attention), MI355X gfx950.
// B=64 N=197 DIM=768 H=12 hd=64. bf16 MFMA (16x16x32), fp32 softmax.
// R12: k_proj rebuilt with the proven T3+T4 pipeline (k_fused/k_prep frozen):
//      - BK=32, superrow-packed LDS (R7's proven layout: 2 rows/64-short
//        superrow, source-swizzled chunks, involution read -> 2-way free).
//      - triple-buffered staging, 48 KB LDS -> 3 blocks/CU (3 waves/SIMD),
//        all 594 blocks co-resident.
//      - counted s_waitcnt vmcnt(4) (4 DMA/wave/phase, depth-2 prefetch),
//        ONE raw s_barrier per phase, no mid-loop full drain.
//      - 4 waves map 1:1 to SIMDs with identical work (balanced).

#define B_    64
#define N_    197
#define DIM_  768
#define H_    12
#define HD_   64
#define M_TOT (B_ * N_)     // 12608

// fused LDS map (shorts): 3 staging buffers (A 13312 + B 12288 each) = 76800
// shorts = 153.6 KB. Q/K/VT (end 40960) overlays A0/A1/A2+B0-head after loop.
#define ST_A0   0
#define ST_A1   13312
#define ST_A2   26624
#define ST_B0   39936
#define ST_B1   52224
#define ST_B2   64512
#define OFF_Q   0            // 208 rows x 64, XOR-swizzled slots
#define OFF_K   13312        // 208 rows x 64
#define OFF_VT  26624        // 64 rows (d) x 224 (tok), group-swizzled
#define LDS_TOT 76800

typedef __attribute__((ext_vector_type(8))) short bf8;
typedef __attribute__((ext_vector_type(4))) float f4;
typedef __attribute__((ext_vector_type(4))) unsigned short us4;

__device__ __forceinline__ unsigned short f2bf(float f) {
    unsigned u = __float_as_uint(f);
    u = (u + 0x7fffu + ((u >> 16) & 1u)) >> 16;
    return (unsigned short)u;
}

__device__ __forceinline__ void gl2lds16(const unsigned short* g, unsigned short* l) {
    __builtin_amdgcn_global_load_lds(
        (const __attribute__((address_space(1))) void*)g,
        (__attribute__((address_space(3))) void*)l, 16, 0, 0);
}

// Q/K LDS address (shorts): row-stride 64, 16B slot XOR-swizzled by row.
__device__ __forceinline__ int qkaddr(int row, int col) {
    return row * 64 + ((((col >> 3) ^ row) & 7) << 3) + (col & 7);
}
// VT LDS address (shorts): d-stride 224; 28 slots/row; XOR within slot groups
// (full 8-groups for s<24, the tail group of 4 uses a 2-bit XOR).
__device__ __forceinline__ int vtaddr(int d, int k) {
    int s = k >> 3;
    int s2 = (s < 24) ? ((s & 24) | ((s ^ d) & 7)) : (24 + ((s ^ d) & 3));
    return d * 224 + (s2 << 3) + (k & 7);
}

// ---------------- prep: fp32->bf16 converts (vectorized), bias gather ----------------
__global__ void k_prep(const float* __restrict__ x, const float* __restrict__ qkvw,
                       const float* __restrict__ projw, const float* __restrict__ rpb,
                       const int* __restrict__ relidx,
                       unsigned short* __restrict__ x_bf, unsigned short* __restrict__ qkvw_bf,
                       unsigned short* __restrict__ projw_bf, float* __restrict__ bias_hqk) {
    const int T = gridDim.x * blockDim.x;
    const int tid = blockIdx.x * blockDim.x + threadIdx.x;
    // all three bulk arrays have elem counts divisible by 4
    for (int i = tid; i < M_TOT * DIM_ / 4; i += T) {
        float4 v = ((const float4*)x)[i];
        us4 o = {f2bf(v.x), f2bf(v.y), f2bf(v.z), f2bf(v.w)};
        ((us4*)x_bf)[i] = o;
    }
    for (int i = tid; i < 3 * DIM_ * DIM_ / 4; i += T) {
        float4 v = ((const float4*)qkvw)[i];
        us4 o = {f2bf(v.x), f2bf(v.y), f2bf(v.z), f2bf(v.w)};
        ((us4*)qkvw_bf)[i] = o;
    }
    for (int i = tid; i < DIM_ * DIM_ / 4; i += T) {
        float4 v = ((const float4*)projw)[i];
        us4 o = {f2bf(v.x), f2bf(v.y), f2bf(v.z), f2bf(v.w)};
        ((us4*)projw_bf)[i] = o;
    }
    for (int i = tid; i < H_ * N_ * N_; i += T) {
        int h = i / (N_ * N_), qk = i - h * (N_ * N_);
        bias_hqk[i] = rpb[relidx[qk] * H_ + h];
    }
}

// ---------------- fused QKV + attention, one block (1024 thr) per (b,h) ----------------
__global__ __launch_bounds__(1024) void k_fused(const unsigned short* __restrict__ X,
                                                const unsigned short* __restrict__ Wqkv,
                                                const float* __restrict__ qb,
                                                const float* __restrict__ vbias,
                                                const float* __restrict__ bias_hqk,
                                                unsigned short* __restrict__ att_ws) {
    __shared__ unsigned short lds[LDS_TOT];

    const int t = threadIdx.x;                 // 0..1023
    const int w = t >> 6, lane = t & 63, ln = lane & 15, quad = lane >> 4;
    const int wm = w >> 2, wn = w & 3;         // SIMD-balanced: SIMD w%4 hosts wm 0..3
    const int srl = lane >> 3;                 // local row 0..7 within 8-row group
    const int src8 = (lane & 7) ^ srl;         // stored-slot -> fetched-chunk XOR swizzle

    // XCD swizzle: gid%8 -> XCD; contiguous 8-b group per XCD keeps x in its L2
    const int gid = blockIdx.x;                // 0..767
    const int local = gid >> 3;                // 0..95
    const int b = (gid & 7) * 8 + (local & 7);
    const int h = local >> 3;                  // 0..11

    const unsigned short* xb = X + (size_t)b * 197 * 768;

    // ---- staging (BK=64): 50 DMA instrs/phase (26 A row-groups + 24 B), 16 waves
    // reversed index: the 4-load waves (14,15) carry the lightest MFMA load (wm=3)
    auto stage = [&](int kt, int aOfs, int bOfs) {
#pragma unroll
        for (int i = 0; i < 4; ++i) {
            int idx = (15 - w) + 16 * i;
            if (idx >= 50) break;              // wave-uniform
            if (idx < 26) {                    // A: token rows idx*8..+7
                int tok = 8 * idx + srl;
                if (tok > 196) tok = 196;      // clamp; pad rows discarded later
                gl2lds16(xb + (size_t)tok * 768 + kt * 64 + src8 * 8,
                         &lds[aOfs + idx * 512]);
            } else {                           // B: weight rows (3 passes x 64)
                int bb = idx - 26;
                int rr = 8 * bb + srl;         // 0..191
                gl2lds16(Wqkv + (size_t)((rr >> 6) * 768 + h * 64 + (rr & 63)) * 768
                              + kt * 64 + src8 * 8,
                         &lds[bOfs + bb * 512]);
            }
        }
    };

    f4 acc[4][3] = {};                         // [mi][tl]: wave tile = (4m x 4n), 12 tiles

    auto compute = [&](int aOfs, int bOfs) {
#pragma unroll
        for (int ks = 0; ks < 2; ++ks) {
            bf8 bfr[3];
#pragma unroll
            for (int tl = 0; tl < 3; ++tl) {
                int rr = (wn * 3 + tl) * 16 + ln;
                int slot = (ks * 4 + quad) ^ (rr & 7);
                bfr[tl] = *(const bf8*)&lds[bOfs + rr * 64 + slot * 8];
            }
            __builtin_amdgcn_s_setprio(1);
#pragma unroll
            for (int mi = 0; mi < 4; ++mi) {
                int mt = wm + 4 * mi;
                if (mt >= 13) continue;        // wave-uniform (only wm>0, mi=3)
                int row = mt * 16 + ln;
                int slot = (ks * 4 + quad) ^ (row & 7);
                bf8 af = *(const bf8*)&lds[aOfs + row * 64 + slot * 8];
#pragma unroll
                for (int tl = 0; tl < 3; ++tl)
                    acc[mi][tl] = __builtin_amdgcn_mfma_f32_16x16x32_bf16(
                        af, bfr[tl], acc[mi][tl], 0, 0, 0);
            }
            __builtin_amdgcn_s_setprio(0);
        }
    };

    // ---- T3+T4 pipelined K-loop: depth-2 prefetch, 1 raw barrier/phase,
    //      counted vmcnt (FIFO completion per m135 makes vmcnt(3) drain
    //      exactly this wave's phase-kt loads while kt+1's stay in flight).
    const int stA[3] = {ST_A0, ST_A1, ST_A2};
    const int stB[3] = {ST_B0, ST_B1, ST_B2};
    stage(0, ST_A0, ST_B0);
    stage(1, ST_A1, ST_B1);
#pragma unroll
    for (int kt = 0; kt < 12; ++kt) {
        if (kt < 11) { __asm__ __volatile__("s_waitcnt vmcnt(3)" ::: "memory"); }
        else         { __asm__ __volatile__("s_waitcnt vmcnt(0)" ::: "memory"); }
        __builtin_amdgcn_sched_barrier(0);
        __builtin_amdgcn_s_barrier();          // buf kt DMA-complete on all waves;
        __builtin_amdgcn_sched_barrier(0);     // buf (kt-1) readers all finished
        if (kt + 2 < 12) stage(kt + 2, stA[(kt + 2) % 3], stB[(kt + 2) % 3]);
        compute(stA[kt % 3], stB[kt % 3]);
    }
    __syncthreads();                           // staging dead: epilogue overlays it

    // ---- epilogue: C/D layout row=quad*4+r, col=ln (m89-verified) -> LDS Q/K/VT
#pragma unroll
    for (int tl = 0; tl < 3; ++tl) {
        int tn = wn * 3 + tl;
        int p = tn >> 2;                       // 0=Q 1=K 2=V
        int col = (tn & 3) * 16 + ln;          // 0..63 within the pass
        int d = h * 64 + col;
        float bj = (p == 0) ? qb[d] : (p == 2) ? vbias[d] : 0.0f;
#pragma unroll
        for (int mi = 0; mi < 4; ++mi) {
            int mt = wm + 4 * mi;
            if (mt >= 13) continue;
#pragma unroll
            for (int r = 0; r < 4; ++r) {
                int row = mt * 16 + quad * 4 + r;  // 0..207 (pad rows masked later)
                float v = acc[mi][tl][r];
                if (p == 0)      lds[OFF_Q + qkaddr(row, col)] = f2bf((v + bj) * 0.125f);
                else if (p == 1) lds[OFF_K + qkaddr(row, col)] = f2bf(v);
                else             lds[OFF_VT + vtaddr(col, row)] = f2bf(v + bj);
            }
        }
    }
    // zero VT K-pad cols 208..223 (cols 197..207 hold finite clamped data)
    for (int idx = t; idx < 64 * 16; idx += 1024) {
        int d = idx >> 4, k = 208 + (idx & 15);
        lds[OFF_VT + vtaddr(d, k)] = 0;
    }
    __syncthreads();

    // ---- attention (Q/K/VT in LDS, P fully in-register), 16 waves, 13 m-tiles ----
    const float* bp = bias_hqk + (size_t)h * 197 * 197;

    for (int mt = w; mt < 13; mt += 16) {
        // Q as B-operand (hoisted): lane ln supplies q-row mt*16+ln
        bf8 qa[2];
#pragma unroll
        for (int ks = 0; ks < 2; ++ks)
            qa[ks] = *(const bf8*)&lds[OFF_Q + qkaddr(mt * 16 + ln, ks * 32 + quad * 8)];

        // swapped QK: S^T[k][q];  lane(ln,quad) reg r holds S[q=mt*16+ln][k=nt*16+quad*4+r]
        f4 sacc[13];
#pragma unroll
        for (int nt = 0; nt < 13; ++nt) sacc[nt] = (f4){0.f, 0.f, 0.f, 0.f};
        __builtin_amdgcn_s_setprio(1);
#pragma unroll
        for (int nt = 0; nt < 13; ++nt) {
#pragma unroll
            for (int ks = 0; ks < 2; ++ks) {
                bf8 ka = *(const bf8*)&lds[OFF_K + qkaddr(nt * 16 + ln, ks * 32 + quad * 8)];
                sacc[nt] = __builtin_amdgcn_mfma_f32_16x16x32_bf16(ka, qa[ks], sacc[nt], 0, 0, 0);
            }
        }
        __builtin_amdgcn_s_setprio(0);

        // softmax: row is lane-local across (nt,r); cross-lane only over quad (2 shfl)
        int qg = mt * 16 + ln;
        const float* brow = bp + (size_t)(qg < 197 ? qg : 196) * 197;
        float mx = -3.0e38f;
#pragma unroll
        for (int nt = 0; nt < 13; ++nt)
#pragma unroll
            for (int r = 0; r < 4; ++r) {
                int kg = nt * 16 + quad * 4 + r;
                float s = (kg < 197) ? (sacc[nt][r] + brow[kg]) : -3.0e38f;
                sacc[nt][r] = s;
                mx = fmaxf(mx, s);
            }
        mx = fmaxf(mx, __shfl_xor(mx, 16, 64));
        mx = fmaxf(mx, __shfl_xor(mx, 32, 64));
        float sum = 0.f;
#pragma unroll
        for (int nt = 0; nt < 13; ++nt)
#pragma unroll
            for (int r = 0; r < 4; ++r) {
                float pv = __expf(sacc[nt][r] - mx);
                sacc[nt][r] = pv;
                sum += pv;
            }
        sum += __shfl_xor(sum, 16, 64);
        sum += __shfl_xor(sum, 32, 64);
        float inv = 1.0f / sum;

        // pack normalized P to bf16 pairs: pk[nt][0]=(r0,r1), pk[nt][1]=(r2,r3)
        unsigned pk[14][2];
#pragma unroll
        for (int nt = 0; nt < 13; ++nt) {
            pk[nt][0] = (unsigned)f2bf(sacc[nt][0] * inv) |
                        ((unsigned)f2bf(sacc[nt][1] * inv) << 16);
            pk[nt][1] = (unsigned)f2bf(sacc[nt][2] * inv) |
                        ((unsigned)f2bf(sacc[nt][3] * inv) << 16);
        }
        pk[13][0] = 0; pk[13][1] = 0;          // K-pad 208..223 -> P = 0

        // PV: A-frag (lane ln = q-row ln, k-chunk = quad*8) built by ds_bpermute:
        // target quad q_t takes k=32ks+8q_t+[0..7] from source lanes
        // (ln + 32*(q_t&1)) and (+16), register set nt = 2ks + (q_t>>1).
        const int sA = (((lane & 15) | ((lane & 16) << 1)) << 2);
        const int sB = sA + 64;
        const bool hi = (lane & 32) != 0;
        f4 o[4];
#pragma unroll
        for (int j = 0; j < 4; ++j) o[j] = (f4){0.f, 0.f, 0.f, 0.f};
#pragma unroll
        for (int ks = 0; ks < 7; ++ks) {
            int b0 = __builtin_amdgcn_ds_bpermute(sA, (int)pk[2 * ks][0]);
            int b1 = __builtin_amdgcn_ds_bpermute(sA, (int)pk[2 * ks][1]);
            int b2 = __builtin_amdgcn_ds_bpermute(sB, (int)pk[2 * ks][0]);
            int b3 = __builtin_amdgcn_ds_bpermute(sB, (int)pk[2 * ks][1]);
            int c0 = __builtin_amdgcn_ds_bpermute(sA, (int)pk[2 * ks + 1][0]);
            int c1 = __builtin_amdgcn_ds_bpermute(sA, (int)pk[2 * ks + 1][1]);
            int c2 = __builtin_amdgcn_ds_bpermute(sB, (int)pk[2 * ks + 1][0]);
            int c3 = __builtin_amdgcn_ds_bpermute(sB, (int)pk[2 * ks + 1][1]);
            union { int u[4]; bf8 v; } uu;
            uu.u[0] = hi ? c0 : b0;
            uu.u[1] = hi ? c1 : b1;
            uu.u[2] = hi ? c2 : b2;
            uu.u[3] = hi ? c3 : b3;
            __builtin_amdgcn_s_setprio(1);
#pragma unroll
            for (int j = 0; j < 4; ++j) {
                bf8 vf = *(const bf8*)&lds[OFF_VT + vtaddr(j * 16 + ln, ks * 32 + quad * 8)];
                o[j] = __builtin_amdgcn_mfma_f32_16x16x32_bf16(uu.v, vf, o[j], 0, 0, 0);
            }
            __builtin_amdgcn_s_setprio(0);
        }
#pragma unroll
        for (int j = 0; j < 4; ++j)
#pragma unroll
            for (int r = 0; r < 4; ++r) {
                int tok = mt * 16 + quad * 4 + r;
                if (tok < 197)
                    att_ws[((size_t)b * 197 + tok) * 768 + h * 64 + j * 16 + ln] = f2bf(o[j][r]);
            }
    }
}

// ---------------- proj GEMM: (12608x768) @ (768x768)^T + bias -> fp32 out ----------------
// R12: BK=32, superrow-packed LDS, triple-buffered, counted vmcnt(4).
// Per buffer (shorts): A 4096 (64 superrows x 64), B 4096. 3 buffers = 24576
// shorts = 48 KB -> 3 blocks/CU (3 waves/SIMD); all 594 blocks co-resident.
#define PJ_BUF 8192

__device__ __forceinline__ void pj_stage(const unsigned short* __restrict__ A,
                                         const unsigned short* __restrict__ Bm,
                                         int bm, int bn, int kt, int w, int srl, int src8,
                                         unsigned short* buf) {
    // superrow sr holds rows {2sr, 2sr+1}, 32 shorts each; chunk c of sr =
    // row 2sr+(c>>2), k-offset (c&3)*8. Stored slot (lane&7) gets fetched
    // chunk src8 = (lane&7)^srl  (involution with the compute-side read).
#pragma unroll
    for (int i = 0; i < 2; ++i) {
        int idx = w * 2 + i;                   // 0..7: superrow group idx*8+srl
        int gr = bm * 128 + 2 * (idx * 8 + srl) + (src8 >> 2);
        if (gr > M_TOT - 1) gr = M_TOT - 1;
        gl2lds16(A + (size_t)gr * 768 + kt * 32 + (src8 & 3) * 8,
                 &buf[idx * 512]);
        int gc = bn * 128 + 2 * (idx * 8 + srl) + (src8 >> 2);   // < 768
        gl2lds16(Bm + (size_t)gc * 768 + kt * 32 + (src8 & 3) * 8,
                 &buf[4096 + idx * 512]);
    }
}

__device__ __forceinline__ void pj_compute(const unsigned short* buf,
                                           int wm, int wn, int ln, int quad, f4 (*acc)[4]) {
    bf8 af[4], bfr[4];
#pragma unroll
    for (int i = 0; i < 4; ++i) {
        int row = wm * 64 + i * 16 + ln;
        int sr = row >> 1;
        int slot = (((row & 1) << 2) | quad) ^ (sr & 7);
        af[i] = *(const bf8*)&buf[sr * 64 + slot * 8];
    }
#pragma unroll
    for (int j = 0; j < 4; ++j) {
        int row = wn * 64 + j * 16 + ln;
        int sr = row >> 1;
        int slot = (((row & 1) << 2) | quad) ^ (sr & 7);
        bfr[j] = *(const bf8*)&buf[4096 + sr * 64 + slot * 8];
    }
    __builtin_amdgcn_s_setprio(1);
#pragma unroll
    for (int i = 0; i < 4; ++i)
#pragma unroll
        for (int j = 0; j < 4; ++j)
            acc[i][j] = __builtin_amdgcn_mfma_f32_16x16x32_bf16(af[i], bfr[j], acc[i][j], 0, 0, 0);
    __builtin_amdgcn_s_setprio(0);
}

__global__ __launch_bounds__(256, 3) void k_proj(const unsigned short* __restrict__ A,
                                                 const unsigned short* __restrict__ Bm,
                                                 const float* __restrict__ pb,
                                                 float* __restrict__ out) {
    __shared__ unsigned short plds[3 * PJ_BUF];
    const int t = threadIdx.x;
    const int w = t >> 6, lane = t & 63, ln = lane & 15, quad = lane >> 4;
    const int wm = w & 1, wn = w >> 1;

    const int gid = blockIdx.x;                 // panels: 8 bm x 6 bn = 48
    const int panel = gid / 48, rem = gid - panel * 48;
    const int pm0 = panel * 8;
    const int psz = (99 - pm0 < 8) ? (99 - pm0) : 8;
    const int bm = pm0 + rem % psz;
    const int bn = rem / psz;

    const int srl = lane >> 3;
    const int src8 = (lane & 7) ^ srl;

    f4 acc[4][4] = {};

    // T3+T4: depth-2 prefetch, 1 raw barrier/phase, counted vmcnt(4)
    // (4 DMA/wave/phase; at the wait, 8 outstanding -> leave kt+1's 4 in flight).
    pj_stage(A, Bm, bm, bn, 0, w, srl, src8, &plds[0]);
    pj_stage(A, Bm, bm, bn, 1, w, srl, src8, &plds[PJ_BUF]);
#pragma unroll
    for (int kt = 0; kt < 24; ++kt) {
        if (kt < 23) { __asm__ __volatile__("s_waitcnt vmcnt(4)" ::: "memory"); }
        else         { __asm__ __volatile__("s_waitcnt vmcnt(0)" ::: "memory"); }
        __builtin_amdgcn_sched_barrier(0);
        __builtin_amdgcn_s_barrier();          // buf kt DMA-complete on all waves;
        __builtin_amdgcn_sched_barrier(0);     // buf (kt-1) readers all finished
        if (kt + 2 < 24) pj_stage(A, Bm, bm, bn, kt + 2, w, srl, src8,
                                  &plds[((kt + 2) % 3) * PJ_BUF]);
        pj_compute(&plds[(kt % 3) * PJ_BUF], wm, wn, ln, quad, acc);
    }

#pragma unroll
    for (int i = 0; i < 4; ++i) {
#pragma unroll
        for (int r = 0; r < 4; ++r) {
            int row_g = bm * 128 + wm * 64 + i * 16 + quad * 4 + r;
            if (row_g >= M_TOT) continue;
#pragma unroll
            for (int j = 0; j < 4; ++j) {
                int col_g = bn * 128 + wn * 64 + j * 16 + ln;
                out[(size_t)row_g * 768 + col_g] = acc[i][j][r] + pb[col_g];
            }
        }
    }
}

extern "C" void kernel_launch(void* const* d_in, const int* in_sizes, int n_in,
                              void* d_out, int out_size, void* d_ws, size_t ws_size,
                              hipStream_t stream) {
    const float* x     = (const float*)d_in[0];
    const float* qkvw  = (const float*)d_in[1];
    const float* qb    = (const float*)d_in[2];
    const float* vb    = (const float*)d_in[3];
    const float* rpb   = (const float*)d_in[4];
    const float* projw = (const float*)d_in[5];
    const float* pb    = (const float*)d_in[6];
    const int*   ridx  = (const int*)d_in[7];
    float* out = (float*)d_out;

    char* ws = (char*)d_ws;
    size_t off = 0;
    auto alloc = [&](size_t bytes) -> void* {
        void* p = ws + off;
        off = (off + bytes + 255) & ~(size_t)255;
        return p;
    };
    unsigned short* x_bf     = (unsigned short*)alloc((size_t)M_TOT * DIM_ * 2);
    unsigned short* qkvw_bf  = (unsigned short*)alloc((size_t)3 * DIM_ * DIM_ * 2);
    unsigned short* projw_bf = (unsigned short*)alloc((size_t)DIM_ * DIM_ * 2);
    float*          bias_h   = (float*)alloc((size_t)H_ * N_ * N_ * 4);
    unsigned short* att_ws   = (unsigned short*)alloc((size_t)(M_TOT + 64) * DIM_ * 2);
    (void)ws_size; (void)in_sizes; (void)n_in; (void)out_size;

    k_prep<<<1200, 256, 0, stream>>>(x, qkvw, projw, rpb, ridx,
                                     x_bf, qkvw_bf, projw_bf, bias_h);
    k_fused<<<768, 1024, 0, stream>>>(x_bf, qkvw_bf, qb, vb, bias_h, att_ws);
    k_proj<<<594, 256, 0, stream>>>(att_ws, projw_bf, pb, out);
}